// Round 8
// baseline (538.920 us; speedup 1.0000x reference)
//
#include <hip/hip_runtime.h>
#include <hip/hip_bf16.h>

#define NN 2048

typedef __attribute__((ext_vector_type(4))) float f32x4;
typedef __attribute__((ext_vector_type(8))) short bf16x8;

__device__ __forceinline__ unsigned short f2bf(float f) {
  __hip_bfloat16 h = __float2bfloat16(f);
  return __builtin_bit_cast(unsigned short, h);
}
__device__ __forceinline__ unsigned int pk2(float a, float b) {
  return (unsigned int)f2bf(a) | ((unsigned int)f2bf(b) << 16);
}
__device__ __forceinline__ void gld_lds16(const void* g, void* l) {
  __builtin_amdgcn_global_load_lds(
      (const __attribute__((address_space(1))) unsigned int*)g,
      (__attribute__((address_space(3))) unsigned int*)l, 16, 0, 0);
}

// Merged transpose+cvt: f32 (R x C) -> bf16 (C x R) for X (batched), W1, W2.
__global__ void k_tr_all(const float* __restrict__ X, unsigned short* __restrict__ XT,
                         const float* __restrict__ W1, unsigned short* __restrict__ W1T,
                         const float* __restrict__ W2, unsigned short* __restrict__ W2T) {
  int bid = blockIdx.x;
  const float* src;
  unsigned short* dst;
  int R, C, bx, by, b;
  if (bid < 8192) {  // X: per batch 64 x 4 tiles, 32 batches
    src = X; dst = XT; R = 2048; C = 128;
    b = bid >> 8;
    int r = bid & 255;
    bx = r & 63; by = r >> 6;
  } else if (bid < 8192 + 32) {  // W1: 128 x 256 -> 4 x 8 tiles
    src = W1; dst = W1T; R = 128; C = 256; b = 0;
    int r = bid - 8192;
    bx = r & 3; by = r >> 2;
  } else {  // W2: 256 x 256 -> 8 x 8 tiles
    src = W2; dst = W2T; R = 256; C = 256; b = 0;
    int r = bid - 8224;
    bx = r & 7; by = r >> 3;
  }
  src += (size_t)b * R * C;
  dst += (size_t)b * R * C;
  __shared__ float tile[32][33];
  int r0 = bx * 32, c0 = by * 32;
  int t = threadIdx.x;
  int r = t >> 3, c4 = (t & 7) << 2;
  float4 v = *(const float4*)(src + (size_t)(r0 + r) * C + c0 + c4);
  tile[r][c4 + 0] = v.x; tile[r][c4 + 1] = v.y; tile[r][c4 + 2] = v.z; tile[r][c4 + 3] = v.w;
  __syncthreads();
  ushort4 o;
  o.x = f2bf(tile[c4 + 0][r]); o.y = f2bf(tile[c4 + 1][r]);
  o.z = f2bf(tile[c4 + 2][r]); o.w = f2bf(tile[c4 + 3][r]);
  *(ushort4*)(dst + (size_t)(c0 + r) * R + r0 + c4) = o;
}

// Fused: T = A[b] (NNxNN f32) @ B[b] (BT given, NCOLS x NN bf16), then
// out = relu(LN(T @ W + bias)) with W^T given (256 x NCOLS bf16).
// MODE 0: write out^T (b,256,NN); MODE 1: per-block column partials -> gpart.
// 512 threads, 8 waves (2 wr x 4 wc). BM=128, BN=NCOLS, BK=64.
// Counted-vmcnt barrier (T4): B gld_lds for kt+1 issued FIRST, then A reg
// loads for kt+2; pre-barrier s_waitcnt vmcnt(4) leaves the 4 A loads in
// flight across the raw s_barrier (no full drain in the main loop).
#define AGG_STEP(KT, AREGC, AREGN, CUR, VMC)                                   \
  {                                                                            \
    const int kt_ = (KT);                                                      \
    if (kt_ < NKT - 1) { /* B tile kt+1 -> Bs[nxt]; issued first (oldest) */   \
      _Pragma("unroll") for (int i = 0; i < NF; ++i) {                         \
        int jj = i * 512 + t;                                                  \
        int n_ = jj >> 3, s_ = jj & 7, sp_ = s_ ^ (n_ & 7);                    \
        gld_lds16(BTb + (size_t)n_ * NN + (size_t)(kt_ + 1) * 64 + sp_ * 8,    \
                  &Bs[(CUR) ^ 1][(i * 512 + wid * 64) * 8]);                   \
      }                                                                        \
    }                                                                          \
    __builtin_amdgcn_sched_barrier(0); /* pin: B ops issue before A ops */     \
    if (kt_ < NKT - 2) { /* A loads for kt+2; stay in flight over barrier */   \
      const float* p_ = apb + (size_t)(kt_ + 2) * 64;                          \
      _Pragma("unroll") for (int j = 0; j < 4; ++j)                            \
          AREGN[j] = ((const float4*)p_)[j];                                   \
    }                                                                          \
    if (kt_ < NKT - 1) { /* cvt A(kt+1) regs (landed long ago) -> As[nxt] */   \
      _Pragma("unroll") for (int i = 0; i < 2; ++i) {                          \
        uint4 w_;                                                              \
        w_.x = pk2(AREGC[2 * i].x, AREGC[2 * i].y);                            \
        w_.y = pk2(AREGC[2 * i].z, AREGC[2 * i].w);                            \
        w_.z = pk2(AREGC[2 * i + 1].x, AREGC[2 * i + 1].y);                    \
        w_.w = pk2(AREGC[2 * i + 1].z, AREGC[2 * i + 1].w);                    \
        int s_ = ak * 2 + i, sp_ = s_ ^ (ar & 7);                              \
        *(uint4*)&As[(CUR) ^ 1][(ar * 8 + sp_) * 8] = w_;                      \
      }                                                                        \
    }                                                                          \
    _Pragma("unroll") for (int kh = 0; kh < 2; ++kh) {                         \
      bf16x8 af[4], bfr[NF];                                                   \
      _Pragma("unroll") for (int mi = 0; mi < 4; ++mi) {                       \
        int row = wr * 64 + mi * 16 + lr;                                      \
        int sp_ = (kh * 4 + q) ^ (row & 7);                                    \
        af[mi] = *(const bf16x8*)&As[CUR][(row * 8 + sp_) * 8];                \
      }                                                                        \
      _Pragma("unroll") for (int ni = 0; ni < NF; ++ni) {                      \
        int brow = wc * WN + ni * 16 + lr;                                     \
        int sp_ = (kh * 4 + q) ^ (brow & 7);                                   \
        bfr[ni] = *(const bf16x8*)&Bs[CUR][(brow * 8 + sp_) * 8];              \
      }                                                                        \
      _Pragma("unroll") for (int mi = 0; mi < 4; ++mi)                         \
        _Pragma("unroll") for (int ni = 0; ni < NF; ++ni)                      \
          acc[mi][ni] = __builtin_amdgcn_mfma_f32_16x16x32_bf16(               \
              af[mi], bfr[ni], acc[mi][ni], 0, 0, 0);                          \
    }                                                                          \
    asm volatile("s_waitcnt vmcnt(" #VMC ") lgkmcnt(0)" ::: "memory");         \
    __builtin_amdgcn_s_barrier();                                              \
  }

template <int NCOLS, int MODE>
__global__ __launch_bounds__(512, NCOLS == 128 ? 4 : 2) void k_agg_fused(
    const float* __restrict__ A, const unsigned short* __restrict__ BT,
    const unsigned short* __restrict__ WT, const float* __restrict__ bias,
    const float* __restrict__ gamma, const float* __restrict__ beta,
    unsigned short* __restrict__ HTout, float* __restrict__ gpart, int bbase) {
  constexpr int WN = NCOLS / 4;   // wave n-width in main loop
  constexpr int NF = NCOLS / 64;  // b-frag count / B-stage iters
  constexpr int NKT = NN / 64;    // 32 K-steps
  constexpr int FIN = NCOLS;      // K of the fused linear
  constexpr int NQT = FIN / 64;   // epilogue K-quarters
  constexpr int NMB = NN / 128;   // m-blocks per batch (16)

  __shared__ __align__(16) unsigned short As[2][128 * 64];
  __shared__ __align__(16) unsigned short Bs[2][NCOLS * 64];
  __shared__ float red[2][128][4];

  // XCD-aware swizzle: all blocks of one batch (sharing the BT panel) land
  // on one XCD, contiguous in dispatch order. Bijective (grid = 128, 8 batches).
  int L = blockIdx.x;
  int xcd = L & 7, slot = L >> 3;
  int mb = slot % NMB;
  int b = bbase + xcd + 8 * (slot / NMB);
  int m0 = mb * 128;

  const float* Ab = A + (size_t)b * NN * NN;
  const unsigned short* BTb = BT + (size_t)b * (size_t)NCOLS * NN;
  int t = threadIdx.x, lane = t & 63, wid = t >> 6;
  int wr = wid >> 2, wc = wid & 3;
  int q = lane >> 4, lr = lane & 15;
  int ar = t >> 2, ak = t & 3;  // A staging: row, 16-f32 chunk
  const float* apb = Ab + (size_t)(m0 + ar) * NN + ak * 16;

  f32x4 acc[4][NF] = {};
  float4 aregA[4], aregB[4];

  // prologue: A(0) loads, B(0) gld_lds, cvt A(0)->As[0], A(1) loads,
  // counted wait (B(0) done, A(1) in flight), barrier.
  {
#pragma unroll
    for (int j = 0; j < 4; ++j) aregA[j] = ((const float4*)apb)[j];
#pragma unroll
    for (int i = 0; i < NF; ++i) {
      int jj = i * 512 + t;
      int n = jj >> 3, s = jj & 7, sp = s ^ (n & 7);
      gld_lds16(BTb + (size_t)n * NN + sp * 8, &Bs[0][(i * 512 + wid * 64) * 8]);
    }
#pragma unroll
    for (int i = 0; i < 2; ++i) {
      uint4 w;
      w.x = pk2(aregA[2 * i].x, aregA[2 * i].y);
      w.y = pk2(aregA[2 * i].z, aregA[2 * i].w);
      w.z = pk2(aregA[2 * i + 1].x, aregA[2 * i + 1].y);
      w.w = pk2(aregA[2 * i + 1].z, aregA[2 * i + 1].w);
      int s = ak * 2 + i, sp = s ^ (ar & 7);
      *(uint4*)&As[0][(ar * 8 + sp) * 8] = w;
    }
    __builtin_amdgcn_sched_barrier(0);
#pragma unroll
    for (int j = 0; j < 4; ++j) aregB[j] = ((const float4*)(apb + 64))[j];
    asm volatile("s_waitcnt vmcnt(4) lgkmcnt(0)" ::: "memory");
    __builtin_amdgcn_s_barrier();
  }

  for (int k2 = 0; k2 < NKT / 2 - 1; ++k2) {
    AGG_STEP(2 * k2, aregB, aregA, 0, 4);
    AGG_STEP(2 * k2 + 1, aregA, aregB, 1, 4);
  }
  AGG_STEP(NKT - 2, aregB, aregA, 0, 0);
  AGG_STEP(NKT - 1, aregA, aregB, 1, 0);

  // ---- epilogue: T(128 x FIN) -> bf16 Hs in LDS (swizzled) ----
  unsigned short* Hs = (NCOLS == 128) ? &As[0][0] : &Bs[0][0];
  unsigned short* Ws = (NCOLS == 128) ? &Bs[0][0] : &As[0][0];
#pragma unroll
  for (int mi = 0; mi < 4; ++mi) {
#pragma unroll
    for (int ni = 0; ni < NF; ++ni) {
#pragma unroll
      for (int j = 0; j < 4; ++j) {
        int row = wr * 64 + mi * 16 + q * 4 + j;
        int col = wc * WN + ni * 16 + lr;
        int sp = (col >> 3) ^ (row & 7);
        Hs[row * FIN + sp * 8 + (col & 7)] = f2bf(acc[mi][ni][j]);
      }
    }
  }

  // ---- linear: acc2 = Hs @ W, W^T staged in K-quarters of [256][64] ----
  f32x4 acc2[4][4] = {};
  for (int qt = 0; qt < NQT; ++qt) {
    __syncthreads();  // Hs visible / previous quarter's Ws reads done
#pragma unroll
    for (int i = 0; i < 4; ++i) {
      int jj = i * 512 + t;
      int h = jj >> 3, s = jj & 7, sp = s ^ (h & 7);
      gld_lds16(WT + (size_t)h * FIN + qt * 64 + sp * 8, Ws + (i * 512 + wid * 64) * 8);
    }
    __syncthreads();
#pragma unroll
    for (int kh = 0; kh < 2; ++kh) {
      bf16x8 hf[4], wf[4];
#pragma unroll
      for (int mi = 0; mi < 4; ++mi) {
        int row = wr * 64 + mi * 16 + lr;
        int slotk = qt * 8 + kh * 4 + q;
        int sp = slotk ^ (row & 7);
        hf[mi] = *(const bf16x8*)&Hs[row * FIN + sp * 8];
      }
#pragma unroll
      for (int ni = 0; ni < 4; ++ni) {
        int h = wc * 64 + ni * 16 + lr;
        int sp = (kh * 4 + q) ^ (h & 7);
        wf[ni] = *(const bf16x8*)&Ws[(h * 8 + sp) * 8];
      }
#pragma unroll
      for (int mi = 0; mi < 4; ++mi) {
#pragma unroll
        for (int ni = 0; ni < 4; ++ni)
          acc2[mi][ni] = __builtin_amdgcn_mfma_f32_16x16x32_bf16(hf[mi], wf[ni], acc2[mi][ni], 0, 0, 0);
      }
    }
  }

  // ---- bias + LayerNorm(256) + relu ----
  float bcol[4], gcol[4], zcol[4];
#pragma unroll
  for (int ni = 0; ni < 4; ++ni) {
    int col = wc * 64 + ni * 16 + lr;
    bcol[ni] = bias[col]; gcol[ni] = gamma[col]; zcol[ni] = beta[col];
  }
#pragma unroll
  for (int mi = 0; mi < 4; ++mi) {
#pragma unroll
    for (int j = 0; j < 4; ++j) {
      float s = 0.f, ss = 0.f;
#pragma unroll
      for (int ni = 0; ni < 4; ++ni) {
        float v = acc2[mi][ni][j] + bcol[ni];
        acc2[mi][ni][j] = v;
        s += v; ss += v * v;
      }
#pragma unroll
      for (int m = 1; m < 16; m <<= 1) { s += __shfl_xor(s, m); ss += __shfl_xor(ss, m); }
      if (lr == 0) {
        int rl = wr * 64 + mi * 16 + q * 4 + j;
        red[0][rl][wc] = s;
        red[1][rl][wc] = ss;
      }
    }
  }
  __syncthreads();
#pragma unroll
  for (int mi = 0; mi < 4; ++mi) {
#pragma unroll
    for (int j = 0; j < 4; ++j) {
      int rl = wr * 64 + mi * 16 + q * 4 + j;
      float s = red[0][rl][0] + red[0][rl][1] + red[0][rl][2] + red[0][rl][3];
      float ss = red[1][rl][0] + red[1][rl][1] + red[1][rl][2] + red[1][rl][3];
      float mean = s * (1.f / 256.f);
      float var = ss * (1.f / 256.f) - mean * mean;
      float inv = rsqrtf(var + 1e-5f);
#pragma unroll
      for (int ni = 0; ni < 4; ++ni) {
        float v = (acc2[mi][ni][j] - mean) * inv * gcol[ni] + zcol[ni];
        acc2[mi][ni][j] = v > 0.f ? v : 0.f;
      }
    }
  }
  if (MODE == 0) {
#pragma unroll
    for (int mi = 0; mi < 4; ++mi) {
#pragma unroll
      for (int ni = 0; ni < 4; ++ni) {
        int col = wc * 64 + ni * 16 + lr;
        int rowb = m0 + wr * 64 + mi * 16 + q * 4;
        ushort4 o;
        o.x = f2bf(acc2[mi][ni][0]); o.y = f2bf(acc2[mi][ni][1]);
        o.z = f2bf(acc2[mi][ni][2]); o.w = f2bf(acc2[mi][ni][3]);
        *(ushort4*)(HTout + ((size_t)b * 256 + col) * NN + rowb) = o;
      }
    }
  } else {
#pragma unroll
    for (int ni = 0; ni < 4; ++ni) {
      float cs = 0.f;
#pragma unroll
      for (int mi = 0; mi < 4; ++mi) {
#pragma unroll
        for (int j = 0; j < 4; ++j) cs += acc2[mi][ni][j];
      }
      cs += __shfl_xor(cs, 16);
      cs += __shfl_xor(cs, 32);
      if (q == 0) {
        int col = wc * 64 + ni * 16 + lr;
        gpart[(((size_t)b * NMB + mb) * 2 + wr) * 256 + col] = cs;
      }
    }
  }
}

__global__ void k_readout(const float* __restrict__ gpart, const float* __restrict__ Wa,
                          const float* __restrict__ ba, const float* __restrict__ Wl,
                          const float* __restrict__ bl, float* __restrict__ out) {
  __shared__ float gl[256];
  int b = blockIdx.x, t = threadIdx.x;  // 256 threads
  float s = 0.f;
#pragma unroll 4
  for (int p = 0; p < 32; ++p) s += gpart[((size_t)b * 32 + p) * 256 + t];
  gl[t] = s * (1.f / 2048.f);
  __syncthreads();
  if (t < 128) {
    int k = t & 63;
    const float* W = (t >= 64) ? Wl : Wa;
    const float* bb = (t >= 64) ? bl : ba;
    float a = 0.f;
    for (int h = 0; h < 256; ++h) a += gl[h] * W[h * 64 + k];
    a += bb[k];
    out[((t >= 64) ? 2048 : 0) + b * 64 + k] = a;
  }
}

extern "C" void kernel_launch(void* const* d_in, const int* in_sizes, int n_in,
                              void* d_out, int out_size, void* d_ws, size_t ws_size,
                              hipStream_t stream) {
  const float* A_hat = (const float*)d_in[0];
  const float* X   = (const float*)d_in[1];
  const float* W1  = (const float*)d_in[2];
  const float* b1  = (const float*)d_in[3];
  const float* g1  = (const float*)d_in[4];
  const float* be1 = (const float*)d_in[5];
  const float* W2  = (const float*)d_in[6];
  const float* b2  = (const float*)d_in[7];
  const float* g2  = (const float*)d_in[8];
  const float* be2 = (const float*)d_in[9];
  const float* Wa  = (const float*)d_in[10];
  const float* ba  = (const float*)d_in[11];
  const float* Wl  = (const float*)d_in[12];
  const float* bl  = (const float*)d_in[13];

  char* ws = (char*)d_ws;
  const size_t MB = 1024 * 1024;
  unsigned short* XT  = (unsigned short*)(ws);                         // 16 MiB (B,128,2048)
  unsigned short* H1T = (unsigned short*)(ws + 16 * MB);               // 32 MiB (B,256,2048)
  unsigned short* W1T = (unsigned short*)(ws + 48 * MB);               // 64 KB (256x128)
  unsigned short* W2T = (unsigned short*)(ws + 48 * MB + 256 * 1024);  // 128 KB (256x256)
  float* gpart        = (float*)(ws + 49 * MB);                        // 1 MiB (B,32,256)

  // prep: transposed bf16 copies (X + W1 + W2 in one launch)
  k_tr_all<<<dim3(8288), 256, 0, stream>>>(X, XT, W1, W1T, W2, W2T);
  // Batch-chunked layer pipeline: chunk of 8 batches (A-chunk = 134 MB)
  // streams through L3 in agg1, then agg2 re-reads the same A from L3
  // instead of HBM. Kernel bodies identical to R7; only batching changed.
  for (int c = 0; c < 4; ++c) {
    k_agg_fused<128, 0><<<dim3(128), 512, 0, stream>>>(
        A_hat, XT, W1T, b1, g1, be1, H1T, nullptr, 8 * c);
    k_agg_fused<256, 1><<<dim3(128), 512, 0, stream>>>(
        A_hat, H1T, W2T, b2, g2, be2, nullptr, gpart, 8 * c);
  }
  // readout
  k_readout<<<dim3(32), 256, 0, stream>>>(gpart, Wa, ba, Wl, bl, (float*)d_out);
}

// Round 9
// 336.680 us; speedup vs baseline: 1.6007x; 1.6007x over previous
//
#include <hip/hip_runtime.h>
#include <hip/hip_bf16.h>

#define NN 2048

typedef __attribute__((ext_vector_type(4))) float f32x4;
typedef __attribute__((ext_vector_type(8))) short bf16x8;

__device__ __forceinline__ unsigned short f2bf(float f) {
  __hip_bfloat16 h = __float2bfloat16(f);
  return __builtin_bit_cast(unsigned short, h);
}
__device__ __forceinline__ unsigned int pk2(float a, float b) {
  return (unsigned int)f2bf(a) | ((unsigned int)f2bf(b) << 16);
}
__device__ __forceinline__ void gld_lds16(const void* g, void* l) {
  __builtin_amdgcn_global_load_lds(
      (const __attribute__((address_space(1))) unsigned int*)g,
      (__attribute__((address_space(3))) unsigned int*)l, 16, 0, 0);
}

// Merged transpose+cvt: f32 (R x C) -> bf16 (C x R) for X (batched), W1, W2.
__global__ void k_tr_all(const float* __restrict__ X, unsigned short* __restrict__ XT,
                         const float* __restrict__ W1, unsigned short* __restrict__ W1T,
                         const float* __restrict__ W2, unsigned short* __restrict__ W2T) {
  int bid = blockIdx.x;
  const float* src;
  unsigned short* dst;
  int R, C, bx, by, b;
  if (bid < 8192) {  // X: per batch 64 x 4 tiles, 32 batches
    src = X; dst = XT; R = 2048; C = 128;
    b = bid >> 8;
    int r = bid & 255;
    bx = r & 63; by = r >> 6;
  } else if (bid < 8192 + 32) {  // W1: 128 x 256 -> 4 x 8 tiles
    src = W1; dst = W1T; R = 128; C = 256; b = 0;
    int r = bid - 8192;
    bx = r & 3; by = r >> 2;
  } else {  // W2: 256 x 256 -> 8 x 8 tiles
    src = W2; dst = W2T; R = 256; C = 256; b = 0;
    int r = bid - 8224;
    bx = r & 7; by = r >> 3;
  }
  src += (size_t)b * R * C;
  dst += (size_t)b * R * C;
  __shared__ float tile[32][33];
  int r0 = bx * 32, c0 = by * 32;
  int t = threadIdx.x;
  int r = t >> 3, c4 = (t & 7) << 2;
  float4 v = *(const float4*)(src + (size_t)(r0 + r) * C + c0 + c4);
  tile[r][c4 + 0] = v.x; tile[r][c4 + 1] = v.y; tile[r][c4 + 2] = v.z; tile[r][c4 + 3] = v.w;
  __syncthreads();
  ushort4 o;
  o.x = f2bf(tile[c4 + 0][r]); o.y = f2bf(tile[c4 + 1][r]);
  o.z = f2bf(tile[c4 + 2][r]); o.w = f2bf(tile[c4 + 3][r]);
  *(ushort4*)(dst + (size_t)(c0 + r) * R + r0 + c4) = o;
}

// Fused: T = A[b] (NNxNN f32) @ B[b] (BT given, NCOLS x NN bf16), then
// out = relu(LN(T @ W + bias)) with W^T given (256 x NCOLS bf16).
// MODE 0: write out^T (b,256,NN); MODE 1: per-block column partials -> gpart.
// 512 threads, 8 waves (2 wr x 4 wc). BM=128, BN=NCOLS, BK=64.
// Counted-vmcnt barrier (T4): B gld_lds for kt+1 issued FIRST, then A reg
// loads for kt+2; pre-barrier s_waitcnt vmcnt(4) leaves the 4 A loads in
// flight across the raw s_barrier (no full drain in the main loop).
#define AGG_STEP(KT, AREGC, AREGN, CUR, VMC)                                   \
  {                                                                            \
    const int kt_ = (KT);                                                      \
    if (kt_ < NKT - 1) { /* B tile kt+1 -> Bs[nxt]; issued first (oldest) */   \
      _Pragma("unroll") for (int i = 0; i < NF; ++i) {                         \
        int jj = i * 512 + t;                                                  \
        int n_ = jj >> 3, s_ = jj & 7, sp_ = s_ ^ (n_ & 7);                    \
        gld_lds16(BTb + (size_t)n_ * NN + (size_t)(kt_ + 1) * 64 + sp_ * 8,    \
                  &Bs[(CUR) ^ 1][(i * 512 + wid * 64) * 8]);                   \
      }                                                                        \
    }                                                                          \
    __builtin_amdgcn_sched_barrier(0); /* pin: B ops issue before A ops */     \
    if (kt_ < NKT - 2) { /* A loads for kt+2; stay in flight over barrier */   \
      const float* p_ = apb + (size_t)(kt_ + 2) * 64;                          \
      _Pragma("unroll") for (int j = 0; j < 4; ++j)                            \
          AREGN[j] = ((const float4*)p_)[j];                                   \
    }                                                                          \
    if (kt_ < NKT - 1) { /* cvt A(kt+1) regs (landed long ago) -> As[nxt] */   \
      _Pragma("unroll") for (int i = 0; i < 2; ++i) {                          \
        uint4 w_;                                                              \
        w_.x = pk2(AREGC[2 * i].x, AREGC[2 * i].y);                            \
        w_.y = pk2(AREGC[2 * i].z, AREGC[2 * i].w);                            \
        w_.z = pk2(AREGC[2 * i + 1].x, AREGC[2 * i + 1].y);                    \
        w_.w = pk2(AREGC[2 * i + 1].z, AREGC[2 * i + 1].w);                    \
        int s_ = ak * 2 + i, sp_ = s_ ^ (ar & 7);                              \
        *(uint4*)&As[(CUR) ^ 1][(ar * 8 + sp_) * 8] = w_;                      \
      }                                                                        \
    }                                                                          \
    _Pragma("unroll") for (int kh = 0; kh < 2; ++kh) {                         \
      bf16x8 af[4], bfr[NF];                                                   \
      _Pragma("unroll") for (int mi = 0; mi < 4; ++mi) {                       \
        int row = wr * 64 + mi * 16 + lr;                                      \
        int sp_ = (kh * 4 + q) ^ (row & 7);                                    \
        af[mi] = *(const bf16x8*)&As[CUR][(row * 8 + sp_) * 8];                \
      }                                                                        \
      _Pragma("unroll") for (int ni = 0; ni < NF; ++ni) {                      \
        int brow = wc * WN + ni * 16 + lr;                                     \
        int sp_ = (kh * 4 + q) ^ (brow & 7);                                   \
        bfr[ni] = *(const bf16x8*)&Bs[CUR][(brow * 8 + sp_) * 8];              \
      }                                                                        \
      _Pragma("unroll") for (int mi = 0; mi < 4; ++mi)                         \
        _Pragma("unroll") for (int ni = 0; ni < NF; ++ni)                      \
          acc[mi][ni] = __builtin_amdgcn_mfma_f32_16x16x32_bf16(               \
              af[mi], bfr[ni], acc[mi][ni], 0, 0, 0);                          \
    }                                                                          \
    asm volatile("s_waitcnt vmcnt(" #VMC ") lgkmcnt(0)" ::: "memory");         \
    __builtin_amdgcn_s_barrier();                                              \
  }

// CHK = batches per launch (grid = CHK*16 blocks). REV=1: visit batches in
// reverse within the chunk (agg2: newest A first -> best L3 LRU hit rate).
template <int NCOLS, int MODE, int CHK, int REV>
__global__ __launch_bounds__(512, NCOLS == 128 ? 4 : 2) void k_agg_fused(
    const float* __restrict__ A, const unsigned short* __restrict__ BT,
    const unsigned short* __restrict__ WT, const float* __restrict__ bias,
    const float* __restrict__ gamma, const float* __restrict__ beta,
    unsigned short* __restrict__ HTout, float* __restrict__ gpart, int bbase) {
  constexpr int WN = NCOLS / 4;   // wave n-width in main loop
  constexpr int NF = NCOLS / 64;  // b-frag count / B-stage iters
  constexpr int NKT = NN / 64;    // 32 K-steps
  constexpr int FIN = NCOLS;      // K of the fused linear
  constexpr int NQT = FIN / 64;   // epilogue K-quarters
  constexpr int NMB = NN / 128;   // m-blocks per batch (16)

  __shared__ __align__(16) unsigned short As[2][128 * 64];
  __shared__ __align__(16) unsigned short Bs[2][NCOLS * 64];
  __shared__ float red[2][128][4];

  // XCD-aware swizzle: all blocks of one batch (sharing the BT panel) land
  // on one XCD, contiguous in dispatch order. Bijective (grid = CHK*16).
  int L = blockIdx.x;
  int xcd = L & 7, slot = L >> 3;
  int mb = slot % NMB;
  int bl = xcd + 8 * (slot / NMB);       // batch-local in [0, CHK)
  if (REV) bl = CHK - 1 - bl;            // newest-first for L3 LRU
  int b = bbase + bl;
  int m0 = mb * 128;

  const float* Ab = A + (size_t)b * NN * NN;
  const unsigned short* BTb = BT + (size_t)b * (size_t)NCOLS * NN;
  int t = threadIdx.x, lane = t & 63, wid = t >> 6;
  int wr = wid >> 2, wc = wid & 3;
  int q = lane >> 4, lr = lane & 15;
  int ar = t >> 2, ak = t & 3;  // A staging: row, 16-f32 chunk
  const float* apb = Ab + (size_t)(m0 + ar) * NN + ak * 16;

  f32x4 acc[4][NF] = {};
  float4 aregA[4], aregB[4];

  // prologue: A(0) loads, B(0) gld_lds, cvt A(0)->As[0], A(1) loads,
  // counted wait (B(0) done, A(1) in flight), barrier.
  {
#pragma unroll
    for (int j = 0; j < 4; ++j) aregA[j] = ((const float4*)apb)[j];
#pragma unroll
    for (int i = 0; i < NF; ++i) {
      int jj = i * 512 + t;
      int n = jj >> 3, s = jj & 7, sp = s ^ (n & 7);
      gld_lds16(BTb + (size_t)n * NN + sp * 8, &Bs[0][(i * 512 + wid * 64) * 8]);
    }
#pragma unroll
    for (int i = 0; i < 2; ++i) {
      uint4 w;
      w.x = pk2(aregA[2 * i].x, aregA[2 * i].y);
      w.y = pk2(aregA[2 * i].z, aregA[2 * i].w);
      w.z = pk2(aregA[2 * i + 1].x, aregA[2 * i + 1].y);
      w.w = pk2(aregA[2 * i + 1].z, aregA[2 * i + 1].w);
      int s = ak * 2 + i, sp = s ^ (ar & 7);
      *(uint4*)&As[0][(ar * 8 + sp) * 8] = w;
    }
    __builtin_amdgcn_sched_barrier(0);
#pragma unroll
    for (int j = 0; j < 4; ++j) aregB[j] = ((const float4*)(apb + 64))[j];
    asm volatile("s_waitcnt vmcnt(4) lgkmcnt(0)" ::: "memory");
    __builtin_amdgcn_s_barrier();
  }

  for (int k2 = 0; k2 < NKT / 2 - 1; ++k2) {
    AGG_STEP(2 * k2, aregB, aregA, 0, 4);
    AGG_STEP(2 * k2 + 1, aregA, aregB, 1, 4);
  }
  AGG_STEP(NKT - 2, aregB, aregA, 0, 0);
  AGG_STEP(NKT - 1, aregA, aregB, 1, 0);

  // ---- epilogue: T(128 x FIN) -> bf16 Hs in LDS (swizzled) ----
  unsigned short* Hs = (NCOLS == 128) ? &As[0][0] : &Bs[0][0];
  unsigned short* Ws = (NCOLS == 128) ? &Bs[0][0] : &As[0][0];
#pragma unroll
  for (int mi = 0; mi < 4; ++mi) {
#pragma unroll
    for (int ni = 0; ni < NF; ++ni) {
#pragma unroll
      for (int j = 0; j < 4; ++j) {
        int row = wr * 64 + mi * 16 + q * 4 + j;
        int col = wc * WN + ni * 16 + lr;
        int sp = (col >> 3) ^ (row & 7);
        Hs[row * FIN + sp * 8 + (col & 7)] = f2bf(acc[mi][ni][j]);
      }
    }
  }

  // ---- linear: acc2 = Hs @ W, W^T staged in K-quarters of [256][64] ----
  f32x4 acc2[4][4] = {};
  for (int qt = 0; qt < NQT; ++qt) {
    __syncthreads();  // Hs visible / previous quarter's Ws reads done
#pragma unroll
    for (int i = 0; i < 4; ++i) {
      int jj = i * 512 + t;
      int h = jj >> 3, s = jj & 7, sp = s ^ (h & 7);
      gld_lds16(WT + (size_t)h * FIN + qt * 64 + sp * 8, Ws + (i * 512 + wid * 64) * 8);
    }
    __syncthreads();
#pragma unroll
    for (int kh = 0; kh < 2; ++kh) {
      bf16x8 hf[4], wf[4];
#pragma unroll
      for (int mi = 0; mi < 4; ++mi) {
        int row = wr * 64 + mi * 16 + lr;
        int slotk = qt * 8 + kh * 4 + q;
        int sp = slotk ^ (row & 7);
        hf[mi] = *(const bf16x8*)&Hs[row * FIN + sp * 8];
      }
#pragma unroll
      for (int ni = 0; ni < 4; ++ni) {
        int h = wc * 64 + ni * 16 + lr;
        int sp = (kh * 4 + q) ^ (h & 7);
        wf[ni] = *(const bf16x8*)&Ws[(h * 8 + sp) * 8];
      }
#pragma unroll
      for (int mi = 0; mi < 4; ++mi) {
#pragma unroll
        for (int ni = 0; ni < 4; ++ni)
          acc2[mi][ni] = __builtin_amdgcn_mfma_f32_16x16x32_bf16(hf[mi], wf[ni], acc2[mi][ni], 0, 0, 0);
      }
    }
  }

  // ---- bias + LayerNorm(256) + relu ----
  float bcol[4], gcol[4], zcol[4];
#pragma unroll
  for (int ni = 0; ni < 4; ++ni) {
    int col = wc * 64 + ni * 16 + lr;
    bcol[ni] = bias[col]; gcol[ni] = gamma[col]; zcol[ni] = beta[col];
  }
#pragma unroll
  for (int mi = 0; mi < 4; ++mi) {
#pragma unroll
    for (int j = 0; j < 4; ++j) {
      float s = 0.f, ss = 0.f;
#pragma unroll
      for (int ni = 0; ni < 4; ++ni) {
        float v = acc2[mi][ni][j] + bcol[ni];
        acc2[mi][ni][j] = v;
        s += v; ss += v * v;
      }
#pragma unroll
      for (int m = 1; m < 16; m <<= 1) { s += __shfl_xor(s, m); ss += __shfl_xor(ss, m); }
      if (lr == 0) {
        int rl = wr * 64 + mi * 16 + q * 4 + j;
        red[0][rl][wc] = s;
        red[1][rl][wc] = ss;
      }
    }
  }
  __syncthreads();
#pragma unroll
  for (int mi = 0; mi < 4; ++mi) {
#pragma unroll
    for (int j = 0; j < 4; ++j) {
      int rl = wr * 64 + mi * 16 + q * 4 + j;
      float s = red[0][rl][0] + red[0][rl][1] + red[0][rl][2] + red[0][rl][3];
      float ss = red[1][rl][0] + red[1][rl][1] + red[1][rl][2] + red[1][rl][3];
      float mean = s * (1.f / 256.f);
      float var = ss * (1.f / 256.f) - mean * mean;
      float inv = rsqrtf(var + 1e-5f);
#pragma unroll
      for (int ni = 0; ni < 4; ++ni) {
        float v = (acc2[mi][ni][j] - mean) * inv * gcol[ni] + zcol[ni];
        acc2[mi][ni][j] = v > 0.f ? v : 0.f;
      }
    }
  }
  if (MODE == 0) {
#pragma unroll
    for (int mi = 0; mi < 4; ++mi) {
#pragma unroll
      for (int ni = 0; ni < 4; ++ni) {
        int col = wc * 64 + ni * 16 + lr;
        int rowb = m0 + wr * 64 + mi * 16 + q * 4;
        ushort4 o;
        o.x = f2bf(acc2[mi][ni][0]); o.y = f2bf(acc2[mi][ni][1]);
        o.z = f2bf(acc2[mi][ni][2]); o.w = f2bf(acc2[mi][ni][3]);
        *(ushort4*)(HTout + ((size_t)b * 256 + col) * NN + rowb) = o;
      }
    }
  } else {
#pragma unroll
    for (int ni = 0; ni < 4; ++ni) {
      float cs = 0.f;
#pragma unroll
      for (int mi = 0; mi < 4; ++mi) {
#pragma unroll
        for (int j = 0; j < 4; ++j) cs += acc2[mi][ni][j];
      }
      cs += __shfl_xor(cs, 16);
      cs += __shfl_xor(cs, 32);
      if (q == 0) {
        int col = wc * 64 + ni * 16 + lr;
        gpart[(((size_t)b * NMB + mb) * 2 + wr) * 256 + col] = cs;
      }
    }
  }
}

__global__ void k_readout(const float* __restrict__ gpart, const float* __restrict__ Wa,
                          const float* __restrict__ ba, const float* __restrict__ Wl,
                          const float* __restrict__ bl, float* __restrict__ out) {
  __shared__ float gl[256];
  int b = blockIdx.x, t = threadIdx.x;  // 256 threads
  float s = 0.f;
#pragma unroll 4
  for (int p = 0; p < 32; ++p) s += gpart[((size_t)b * 32 + p) * 256 + t];
  gl[t] = s * (1.f / 2048.f);
  __syncthreads();
  if (t < 128) {
    int k = t & 63;
    const float* W = (t >= 64) ? Wl : Wa;
    const float* bb = (t >= 64) ? bl : ba;
    float a = 0.f;
    for (int h = 0; h < 256; ++h) a += gl[h] * W[h * 64 + k];
    a += bb[k];
    out[((t >= 64) ? 2048 : 0) + b * 64 + k] = a;
  }
}

extern "C" void kernel_launch(void* const* d_in, const int* in_sizes, int n_in,
                              void* d_out, int out_size, void* d_ws, size_t ws_size,
                              hipStream_t stream) {
  const float* A_hat = (const float*)d_in[0];
  const float* X   = (const float*)d_in[1];
  const float* W1  = (const float*)d_in[2];
  const float* b1  = (const float*)d_in[3];
  const float* g1  = (const float*)d_in[4];
  const float* be1 = (const float*)d_in[5];
  const float* W2  = (const float*)d_in[6];
  const float* b2  = (const float*)d_in[7];
  const float* g2  = (const float*)d_in[8];
  const float* be2 = (const float*)d_in[9];
  const float* Wa  = (const float*)d_in[10];
  const float* ba  = (const float*)d_in[11];
  const float* Wl  = (const float*)d_in[12];
  const float* bl  = (const float*)d_in[13];

  char* ws = (char*)d_ws;
  const size_t MB = 1024 * 1024;
  unsigned short* XT  = (unsigned short*)(ws);                         // 16 MiB (B,128,2048)
  unsigned short* H1T = (unsigned short*)(ws + 16 * MB);               // 32 MiB (B,256,2048)
  unsigned short* W1T = (unsigned short*)(ws + 48 * MB);               // 64 KB (256x128)
  unsigned short* W2T = (unsigned short*)(ws + 48 * MB + 256 * 1024);  // 128 KB (256x256)
  float* gpart        = (float*)(ws + 49 * MB);                        // 1 MiB (B,32,256)

  // prep: transposed bf16 copies (X + W1 + W2 in one launch)
  k_tr_all<<<dim3(8288), 256, 0, stream>>>(X, XT, W1, W1T, W2, W2T);
  // Chunked layer pipeline at FULL grid width: chunk = 16 batches -> 256
  // blocks (every CU covered). agg1(c) streams A-chunk (268 MB ~= L3);
  // agg2(c) re-reads it newest-first (REV) from Infinity Cache.
  for (int c = 0; c < 2; ++c) {
    k_agg_fused<128, 0, 16, 0><<<dim3(256), 512, 0, stream>>>(
        A_hat, XT, W1T, b1, g1, be1, H1T, nullptr, 16 * c);
    k_agg_fused<256, 1, 16, 1><<<dim3(256), 512, 0, stream>>>(
        A_hat, H1T, W2T, b2, g2, be2, nullptr, gpart, 16 * c);
  }
  // readout
  k_readout<<<dim3(32), 256, 0, stream>>>(gpart, Wa, ba, Wl, bl, (float*)d_out);
}

// Round 10
// 330.874 us; speedup vs baseline: 1.6288x; 1.0175x over previous
//
#include <hip/hip_runtime.h>
#include <hip/hip_bf16.h>

#define NN 2048

typedef __attribute__((ext_vector_type(4))) float f32x4;
typedef __attribute__((ext_vector_type(8))) short bf16x8;

__device__ __forceinline__ unsigned short f2bf(float f) {
  __hip_bfloat16 h = __float2bfloat16(f);
  return __builtin_bit_cast(unsigned short, h);
}
__device__ __forceinline__ unsigned int pk2(float a, float b) {
  return (unsigned int)f2bf(a) | ((unsigned int)f2bf(b) << 16);
}
__device__ __forceinline__ void gld_lds16(const void* g, void* l) {
  __builtin_amdgcn_global_load_lds(
      (const __attribute__((address_space(1))) unsigned int*)g,
      (__attribute__((address_space(3))) unsigned int*)l, 16, 0, 0);
}

// Merged transpose+cvt: f32 (R x C) -> bf16 (C x R) for X (batched), W1, W2.
__global__ void k_tr_all(const float* __restrict__ X, unsigned short* __restrict__ XT,
                         const float* __restrict__ W1, unsigned short* __restrict__ W1T,
                         const float* __restrict__ W2, unsigned short* __restrict__ W2T) {
  int bid = blockIdx.x;
  const float* src;
  unsigned short* dst;
  int R, C, bx, by, b;
  if (bid < 8192) {  // X: per batch 64 x 4 tiles, 32 batches
    src = X; dst = XT; R = 2048; C = 128;
    b = bid >> 8;
    int r = bid & 255;
    bx = r & 63; by = r >> 6;
  } else if (bid < 8192 + 32) {  // W1: 128 x 256 -> 4 x 8 tiles
    src = W1; dst = W1T; R = 128; C = 256; b = 0;
    int r = bid - 8192;
    bx = r & 3; by = r >> 2;
  } else {  // W2: 256 x 256 -> 8 x 8 tiles
    src = W2; dst = W2T; R = 256; C = 256; b = 0;
    int r = bid - 8224;
    bx = r & 7; by = r >> 3;
  }
  src += (size_t)b * R * C;
  dst += (size_t)b * R * C;
  __shared__ float tile[32][33];
  int r0 = bx * 32, c0 = by * 32;
  int t = threadIdx.x;
  int r = t >> 3, c4 = (t & 7) << 2;
  float4 v = *(const float4*)(src + (size_t)(r0 + r) * C + c0 + c4);
  tile[r][c4 + 0] = v.x; tile[r][c4 + 1] = v.y; tile[r][c4 + 2] = v.z; tile[r][c4 + 3] = v.w;
  __syncthreads();
  ushort4 o;
  o.x = f2bf(tile[c4 + 0][r]); o.y = f2bf(tile[c4 + 1][r]);
  o.z = f2bf(tile[c4 + 2][r]); o.w = f2bf(tile[c4 + 3][r]);
  *(ushort4*)(dst + (size_t)(c0 + r) * R + r0 + c4) = o;
}

// ---------------- Layer-1 fused kernel (R7-proven, unchanged) ----------------
#define AGG_STEP(KT, AREGC, AREGN, CUR, VMC)                                   \
  {                                                                            \
    const int kt_ = (KT);                                                      \
    if (kt_ < NKT - 1) { /* B tile kt+1 -> Bs[nxt]; issued first (oldest) */   \
      _Pragma("unroll") for (int i = 0; i < NF; ++i) {                         \
        int jj = i * 512 + t;                                                  \
        int n_ = jj >> 3, s_ = jj & 7, sp_ = s_ ^ (n_ & 7);                    \
        gld_lds16(BTb + (size_t)n_ * NN + (size_t)(kt_ + 1) * 64 + sp_ * 8,    \
                  &Bs[(CUR) ^ 1][(i * 512 + wid * 64) * 8]);                   \
      }                                                                        \
    }                                                                          \
    __builtin_amdgcn_sched_barrier(0); /* pin: B ops issue before A ops */     \
    if (kt_ < NKT - 2) { /* A loads for kt+2; stay in flight over barrier */   \
      const float* p_ = apb + (size_t)(kt_ + 2) * 64;                          \
      _Pragma("unroll") for (int j = 0; j < 4; ++j)                            \
          AREGN[j] = ((const float4*)p_)[j];                                   \
    }                                                                          \
    if (kt_ < NKT - 1) { /* cvt A(kt+1) regs (landed long ago) -> As[nxt] */   \
      _Pragma("unroll") for (int i = 0; i < 2; ++i) {                          \
        uint4 w_;                                                              \
        w_.x = pk2(AREGC[2 * i].x, AREGC[2 * i].y);                            \
        w_.y = pk2(AREGC[2 * i].z, AREGC[2 * i].w);                            \
        w_.z = pk2(AREGC[2 * i + 1].x, AREGC[2 * i + 1].y);                    \
        w_.w = pk2(AREGC[2 * i + 1].z, AREGC[2 * i + 1].w);                    \
        int s_ = ak * 2 + i, sp_ = s_ ^ (ar & 7);                              \
        *(uint4*)&As[(CUR) ^ 1][(ar * 8 + sp_) * 8] = w_;                      \
      }                                                                        \
    }                                                                          \
    _Pragma("unroll") for (int kh = 0; kh < 2; ++kh) {                         \
      bf16x8 af[4], bfr[NF];                                                   \
      _Pragma("unroll") for (int mi = 0; mi < 4; ++mi) {                       \
        int row = wr * 64 + mi * 16 + lr;                                      \
        int sp_ = (kh * 4 + q) ^ (row & 7);                                    \
        af[mi] = *(const bf16x8*)&As[CUR][(row * 8 + sp_) * 8];                \
      }                                                                        \
      _Pragma("unroll") for (int ni = 0; ni < NF; ++ni) {                      \
        int brow = wc * WN + ni * 16 + lr;                                     \
        int sp_ = (kh * 4 + q) ^ (brow & 7);                                   \
        bfr[ni] = *(const bf16x8*)&Bs[CUR][(brow * 8 + sp_) * 8];              \
      }                                                                        \
      _Pragma("unroll") for (int mi = 0; mi < 4; ++mi)                         \
        _Pragma("unroll") for (int ni = 0; ni < NF; ++ni)                      \
          acc[mi][ni] = __builtin_amdgcn_mfma_f32_16x16x32_bf16(               \
              af[mi], bfr[ni], acc[mi][ni], 0, 0, 0);                          \
    }                                                                          \
    asm volatile("s_waitcnt vmcnt(" #VMC ") lgkmcnt(0)" ::: "memory");         \
    __builtin_amdgcn_s_barrier();                                              \
  }

template <int NCOLS, int MODE>
__global__ __launch_bounds__(512, NCOLS == 128 ? 4 : 2) void k_agg_fused(
    const float* __restrict__ A, const unsigned short* __restrict__ BT,
    const unsigned short* __restrict__ WT, const float* __restrict__ bias,
    const float* __restrict__ gamma, const float* __restrict__ beta,
    unsigned short* __restrict__ HTout, float* __restrict__ gpart) {
  constexpr int WN = NCOLS / 4;
  constexpr int NF = NCOLS / 64;
  constexpr int NKT = NN / 64;
  constexpr int FIN = NCOLS;
  constexpr int NQT = FIN / 64;
  constexpr int NMB = NN / 128;

  __shared__ __align__(16) unsigned short As[2][128 * 64];
  __shared__ __align__(16) unsigned short Bs[2][NCOLS * 64];
  __shared__ float red[2][128][4];

  int L = blockIdx.x + gridDim.x * blockIdx.z;
  int xcd = L & 7, slot = L >> 3;
  int mb = slot % NMB;
  int b = xcd + 8 * (slot / NMB);
  int m0 = mb * 128;

  const float* Ab = A + (size_t)b * NN * NN;
  const unsigned short* BTb = BT + (size_t)b * (size_t)NCOLS * NN;
  int t = threadIdx.x, lane = t & 63, wid = t >> 6;
  int wr = wid >> 2, wc = wid & 3;
  int q = lane >> 4, lr = lane & 15;
  int ar = t >> 2, ak = t & 3;
  const float* apb = Ab + (size_t)(m0 + ar) * NN + ak * 16;

  f32x4 acc[4][NF] = {};
  float4 aregA[4], aregB[4];

  {
#pragma unroll
    for (int j = 0; j < 4; ++j) aregA[j] = ((const float4*)apb)[j];
#pragma unroll
    for (int i = 0; i < NF; ++i) {
      int jj = i * 512 + t;
      int n = jj >> 3, s = jj & 7, sp = s ^ (n & 7);
      gld_lds16(BTb + (size_t)n * NN + sp * 8, &Bs[0][(i * 512 + wid * 64) * 8]);
    }
#pragma unroll
    for (int i = 0; i < 2; ++i) {
      uint4 w;
      w.x = pk2(aregA[2 * i].x, aregA[2 * i].y);
      w.y = pk2(aregA[2 * i].z, aregA[2 * i].w);
      w.z = pk2(aregA[2 * i + 1].x, aregA[2 * i + 1].y);
      w.w = pk2(aregA[2 * i + 1].z, aregA[2 * i + 1].w);
      int s = ak * 2 + i, sp = s ^ (ar & 7);
      *(uint4*)&As[0][(ar * 8 + sp) * 8] = w;
    }
    __builtin_amdgcn_sched_barrier(0);
#pragma unroll
    for (int j = 0; j < 4; ++j) aregB[j] = ((const float4*)(apb + 64))[j];
    asm volatile("s_waitcnt vmcnt(4) lgkmcnt(0)" ::: "memory");
    __builtin_amdgcn_s_barrier();
  }

  for (int k2 = 0; k2 < NKT / 2 - 1; ++k2) {
    AGG_STEP(2 * k2, aregB, aregA, 0, 4);
    AGG_STEP(2 * k2 + 1, aregA, aregB, 1, 4);
  }
  AGG_STEP(NKT - 2, aregB, aregA, 0, 0);
  AGG_STEP(NKT - 1, aregA, aregB, 1, 0);

  unsigned short* Hs = (NCOLS == 128) ? &As[0][0] : &Bs[0][0];
  unsigned short* Ws = (NCOLS == 128) ? &Bs[0][0] : &As[0][0];
#pragma unroll
  for (int mi = 0; mi < 4; ++mi) {
#pragma unroll
    for (int ni = 0; ni < NF; ++ni) {
#pragma unroll
      for (int j = 0; j < 4; ++j) {
        int row = wr * 64 + mi * 16 + q * 4 + j;
        int col = wc * WN + ni * 16 + lr;
        int sp = (col >> 3) ^ (row & 7);
        Hs[row * FIN + sp * 8 + (col & 7)] = f2bf(acc[mi][ni][j]);
      }
    }
  }

  f32x4 acc2[4][4] = {};
  for (int qt = 0; qt < NQT; ++qt) {
    __syncthreads();
#pragma unroll
    for (int i = 0; i < 4; ++i) {
      int jj = i * 512 + t;
      int h = jj >> 3, s = jj & 7, sp = s ^ (h & 7);
      gld_lds16(WT + (size_t)h * FIN + qt * 64 + sp * 8, Ws + (i * 512 + wid * 64) * 8);
    }
    __syncthreads();
#pragma unroll
    for (int kh = 0; kh < 2; ++kh) {
      bf16x8 hf[4], wf[4];
#pragma unroll
      for (int mi = 0; mi < 4; ++mi) {
        int row = wr * 64 + mi * 16 + lr;
        int slotk = qt * 8 + kh * 4 + q;
        int sp = slotk ^ (row & 7);
        hf[mi] = *(const bf16x8*)&Hs[row * FIN + sp * 8];
      }
#pragma unroll
      for (int ni = 0; ni < 4; ++ni) {
        int h = wc * 64 + ni * 16 + lr;
        int sp = (kh * 4 + q) ^ (h & 7);
        wf[ni] = *(const bf16x8*)&Ws[(h * 8 + sp) * 8];
      }
#pragma unroll
      for (int mi = 0; mi < 4; ++mi) {
#pragma unroll
        for (int ni = 0; ni < 4; ++ni)
          acc2[mi][ni] = __builtin_amdgcn_mfma_f32_16x16x32_bf16(hf[mi], wf[ni], acc2[mi][ni], 0, 0, 0);
      }
    }
  }

  float bcol[4], gcol[4], zcol[4];
#pragma unroll
  for (int ni = 0; ni < 4; ++ni) {
    int col = wc * 64 + ni * 16 + lr;
    bcol[ni] = bias[col]; gcol[ni] = gamma[col]; zcol[ni] = beta[col];
  }
#pragma unroll
  for (int mi = 0; mi < 4; ++mi) {
#pragma unroll
    for (int j = 0; j < 4; ++j) {
      float s = 0.f, ss = 0.f;
#pragma unroll
      for (int ni = 0; ni < 4; ++ni) {
        float v = acc2[mi][ni][j] + bcol[ni];
        acc2[mi][ni][j] = v;
        s += v; ss += v * v;
      }
#pragma unroll
      for (int m = 1; m < 16; m <<= 1) { s += __shfl_xor(s, m); ss += __shfl_xor(ss, m); }
      if (lr == 0) {
        int rl = wr * 64 + mi * 16 + q * 4 + j;
        red[0][rl][wc] = s;
        red[1][rl][wc] = ss;
      }
    }
  }
  __syncthreads();
#pragma unroll
  for (int mi = 0; mi < 4; ++mi) {
#pragma unroll
    for (int j = 0; j < 4; ++j) {
      int rl = wr * 64 + mi * 16 + q * 4 + j;
      float s = red[0][rl][0] + red[0][rl][1] + red[0][rl][2] + red[0][rl][3];
      float ss = red[1][rl][0] + red[1][rl][1] + red[1][rl][2] + red[1][rl][3];
      float mean = s * (1.f / 256.f);
      float var = ss * (1.f / 256.f) - mean * mean;
      float inv = rsqrtf(var + 1e-5f);
#pragma unroll
      for (int ni = 0; ni < 4; ++ni) {
        float v = (acc2[mi][ni][j] - mean) * inv * gcol[ni] + zcol[ni];
        acc2[mi][ni][j] = v > 0.f ? v : 0.f;
      }
    }
  }
  if (MODE == 0) {
#pragma unroll
    for (int mi = 0; mi < 4; ++mi) {
#pragma unroll
      for (int ni = 0; ni < 4; ++ni) {
        int col = wc * 64 + ni * 16 + lr;
        int rowb = m0 + wr * 64 + mi * 16 + q * 4;
        ushort4 o;
        o.x = f2bf(acc2[mi][ni][0]); o.y = f2bf(acc2[mi][ni][1]);
        o.z = f2bf(acc2[mi][ni][2]); o.w = f2bf(acc2[mi][ni][3]);
        *(ushort4*)(HTout + ((size_t)b * 256 + col) * NN + rowb) = o;
      }
    }
  } else {
#pragma unroll
    for (int ni = 0; ni < 4; ++ni) {
      float cs = 0.f;
#pragma unroll
      for (int mi = 0; mi < 4; ++mi) {
#pragma unroll
        for (int j = 0; j < 4; ++j) cs += acc2[mi][ni][j];
      }
      cs += __shfl_xor(cs, 16);
      cs += __shfl_xor(cs, 32);
      if (q == 0) {
        int col = wc * 64 + ni * 16 + lr;
        gpart[(((size_t)b * NMB + mb) * 2 + wr) * 256 + col] = cs;
      }
    }
  }
}

// ---------------- Layer-2 fused kernel: 80 KB LDS -> 2 blocks/CU ----------------
// Single-buffered As (16 KB) + double-buffered Bs (64 KB). Split-barrier step:
//   {issue B(kt+1), issue A(kt+1), MFMA(As,Bs[cur]), lgkm-barrier,
//    cvt A(kt+1)->As, vmcnt(0)+lgkm-barrier}
// First barrier does NOT drain vmcnt: B loads fly through the cvt phase; the
// cvt gap + B latency are hidden by the co-resident block (occupancy 2).
__global__ __launch_bounds__(512, 4) void k_agg2(
    const float* __restrict__ A, const unsigned short* __restrict__ BT,
    const unsigned short* __restrict__ WT, const float* __restrict__ bias,
    const float* __restrict__ gamma, const float* __restrict__ beta,
    float* __restrict__ gpart) {
  constexpr int NKT = 32;
  constexpr int NMB = 16;

  __shared__ __align__(16) unsigned short As1[128 * 64];    // 16 KB, single buf
  __shared__ __align__(16) unsigned short Bs[2][256 * 64];  // 64 KB
  float* redp = (float*)As1;  // overlay, live only after Ws reads done

  int L = blockIdx.x + gridDim.x * blockIdx.z;
  int xcd = L & 7, slot = L >> 3;
  int mb = slot % NMB;
  int b = xcd + 8 * (slot / NMB);
  int m0 = mb * 128;

  const float* Ab = A + (size_t)b * NN * NN;
  const unsigned short* BTb = BT + (size_t)b * (size_t)256 * NN;
  int t = threadIdx.x, lane = t & 63, wid = t >> 6;
  int wr = wid >> 2, wc = wid & 3;
  int q = lane >> 4, lr = lane & 15;
  int ar = t >> 2, ak = t & 3;
  const float* apb = Ab + (size_t)(m0 + ar) * NN + ak * 16;

  f32x4 acc[4][4] = {};
  float4 areg[4];

  // prologue: A(0)->regs, B(0)->Bs[0], cvt A(0)->As1, full drain, barrier.
  {
#pragma unroll
    for (int j = 0; j < 4; ++j) areg[j] = ((const float4*)apb)[j];
#pragma unroll
    for (int i = 0; i < 4; ++i) {
      int jj = i * 512 + t;
      int n = jj >> 3, s = jj & 7, sp = s ^ (n & 7);
      gld_lds16(BTb + (size_t)n * NN + sp * 8, &Bs[0][(i * 512 + wid * 64) * 8]);
    }
#pragma unroll
    for (int i = 0; i < 2; ++i) {
      uint4 w;
      w.x = pk2(areg[2 * i].x, areg[2 * i].y);
      w.y = pk2(areg[2 * i].z, areg[2 * i].w);
      w.z = pk2(areg[2 * i + 1].x, areg[2 * i + 1].y);
      w.w = pk2(areg[2 * i + 1].z, areg[2 * i + 1].w);
      int s = ak * 2 + i, sp = s ^ (ar & 7);
      *(uint4*)&As1[(ar * 8 + sp) * 8] = w;
    }
    asm volatile("s_waitcnt vmcnt(0) lgkmcnt(0)" ::: "memory");
    __builtin_amdgcn_s_barrier();
  }

  for (int kt = 0; kt < NKT; ++kt) {
    int cur = kt & 1;
    unsigned short* bnx = &Bs[cur ^ 1][0];
    const unsigned short* bcu = &Bs[cur][0];
    if (kt < NKT - 1) {  // B tile kt+1 (oldest vmem ops of this step)
#pragma unroll
      for (int i = 0; i < 4; ++i) {
        int jj = i * 512 + t;
        int n = jj >> 3, s = jj & 7, sp = s ^ (n & 7);
        gld_lds16(BTb + (size_t)n * NN + (size_t)(kt + 1) * 64 + sp * 8,
                  bnx + (i * 512 + wid * 64) * 8);
      }
    }
    __builtin_amdgcn_sched_barrier(0);
    if (kt < NKT - 1) {  // A tile kt+1 -> regs
      const float* p = apb + (size_t)(kt + 1) * 64;
#pragma unroll
      for (int j = 0; j < 4; ++j) areg[j] = ((const float4*)p)[j];
    }
#pragma unroll
    for (int kh = 0; kh < 2; ++kh) {
      bf16x8 af[4], bfr[4];
#pragma unroll
      for (int mi = 0; mi < 4; ++mi) {
        int row = wr * 64 + mi * 16 + lr;
        int sp = (kh * 4 + q) ^ (row & 7);
        af[mi] = *(const bf16x8*)&As1[(row * 8 + sp) * 8];
      }
#pragma unroll
      for (int ni = 0; ni < 4; ++ni) {
        int brow = wc * 64 + ni * 16 + lr;
        int sp = (kh * 4 + q) ^ (brow & 7);
        bfr[ni] = *(const bf16x8*)(bcu + (brow * 8 + sp) * 8);
      }
#pragma unroll
      for (int mi = 0; mi < 4; ++mi)
#pragma unroll
        for (int ni = 0; ni < 4; ++ni)
          acc[mi][ni] = __builtin_amdgcn_mfma_f32_16x16x32_bf16(af[mi], bfr[ni], acc[mi][ni], 0, 0, 0);
    }
    // barrier 1: all As1/Bs reads retired; vmcnt NOT drained (B keeps flying)
    asm volatile("s_waitcnt lgkmcnt(0)" ::: "memory");
    __builtin_amdgcn_s_barrier();
    __builtin_amdgcn_sched_barrier(0);
    if (kt < NKT - 1) {  // cvt A(kt+1) -> As1 (reg dep auto-waits the A loads)
#pragma unroll
      for (int i = 0; i < 2; ++i) {
        uint4 w;
        w.x = pk2(areg[2 * i].x, areg[2 * i].y);
        w.y = pk2(areg[2 * i].z, areg[2 * i].w);
        w.z = pk2(areg[2 * i + 1].x, areg[2 * i + 1].y);
        w.w = pk2(areg[2 * i + 1].z, areg[2 * i + 1].w);
        int s = ak * 2 + i, sp = s ^ (ar & 7);
        *(uint4*)&As1[(ar * 8 + sp) * 8] = w;
      }
    }
    // barrier 2: B(kt+1) landed + As1 writes visible
    asm volatile("s_waitcnt vmcnt(0) lgkmcnt(0)" ::: "memory");
    __builtin_amdgcn_s_barrier();
  }

  // ---- epilogue: T(128 x 256) -> Hs (= whole Bs region, 64 KB) ----
  unsigned short* Hs = &Bs[0][0];
#pragma unroll
  for (int mi = 0; mi < 4; ++mi) {
#pragma unroll
    for (int ni = 0; ni < 4; ++ni) {
#pragma unroll
      for (int j = 0; j < 4; ++j) {
        int row = wr * 64 + mi * 16 + q * 4 + j;
        int col = wc * 64 + ni * 16 + lr;
        int sp = (col >> 3) ^ (row & 7);
        Hs[row * 256 + sp * 8 + (col & 7)] = f2bf(acc[mi][ni][j]);
      }
    }
  }

  // ---- linear: acc2 = Hs @ W2, W^T staged in EIGHTHS (256 x 32 = 16 KB in As1) ----
  f32x4 acc2[4][4] = {};
  for (int qt = 0; qt < 8; ++qt) {
    // prev eighth's Ws reads (and for qt=0 the Hs writes) retired
    asm volatile("s_waitcnt lgkmcnt(0)" ::: "memory");
    __builtin_amdgcn_s_barrier();
#pragma unroll
    for (int i = 0; i < 2; ++i) {
      int jj = i * 512 + t;
      int h = jj >> 2, spp = jj & 3, spl = spp ^ (h & 3);
      gld_lds16(WT + (size_t)h * 256 + qt * 32 + spl * 8,
                &As1[(i * 512 + wid * 64) * 8]);
    }
    asm volatile("s_waitcnt vmcnt(0) lgkmcnt(0)" ::: "memory");
    __builtin_amdgcn_s_barrier();
    bf16x8 hf[4], wf[4];
#pragma unroll
    for (int mi = 0; mi < 4; ++mi) {
      int row = wr * 64 + mi * 16 + lr;
      int slotk = qt * 4 + q;
      int sp = slotk ^ (row & 7);
      hf[mi] = *(const bf16x8*)&Hs[row * 256 + sp * 8];
    }
#pragma unroll
    for (int ni = 0; ni < 4; ++ni) {
      int h = wc * 64 + ni * 16 + lr;
      int sp = q ^ (h & 3);
      wf[ni] = *(const bf16x8*)&As1[(h * 4 + sp) * 8];
    }
#pragma unroll
    for (int mi = 0; mi < 4; ++mi)
#pragma unroll
      for (int ni = 0; ni < 4; ++ni)
        acc2[mi][ni] = __builtin_amdgcn_mfma_f32_16x16x32_bf16(hf[mi], wf[ni], acc2[mi][ni], 0, 0, 0);
  }
  asm volatile("s_waitcnt lgkmcnt(0)" ::: "memory");
  __builtin_amdgcn_s_barrier();  // Ws reads done before redp overlay goes live

  // ---- bias + LayerNorm(256) + relu + column partials ----
  float bcol[4], gcol[4], zcol[4];
#pragma unroll
  for (int ni = 0; ni < 4; ++ni) {
    int col = wc * 64 + ni * 16 + lr;
    bcol[ni] = bias[col]; gcol[ni] = gamma[col]; zcol[ni] = beta[col];
  }
#pragma unroll
  for (int mi = 0; mi < 4; ++mi) {
#pragma unroll
    for (int j = 0; j < 4; ++j) {
      float s = 0.f, ss = 0.f;
#pragma unroll
      for (int ni = 0; ni < 4; ++ni) {
        float v = acc2[mi][ni][j] + bcol[ni];
        acc2[mi][ni][j] = v;
        s += v; ss += v * v;
      }
#pragma unroll
      for (int m = 1; m < 16; m <<= 1) { s += __shfl_xor(s, m); ss += __shfl_xor(ss, m); }
      if (lr == 0) {
        int rl = wr * 64 + mi * 16 + q * 4 + j;
        redp[(0 * 128 + rl) * 4 + wc] = s;
        redp[(1 * 128 + rl) * 4 + wc] = ss;
      }
    }
  }
  __syncthreads();
#pragma unroll
  for (int mi = 0; mi < 4; ++mi) {
#pragma unroll
    for (int j = 0; j < 4; ++j) {
      int rl = wr * 64 + mi * 16 + q * 4 + j;
      float s = redp[(0 * 128 + rl) * 4 + 0] + redp[(0 * 128 + rl) * 4 + 1] +
                redp[(0 * 128 + rl) * 4 + 2] + redp[(0 * 128 + rl) * 4 + 3];
      float ss = redp[(1 * 128 + rl) * 4 + 0] + redp[(1 * 128 + rl) * 4 + 1] +
                 redp[(1 * 128 + rl) * 4 + 2] + redp[(1 * 128 + rl) * 4 + 3];
      float mean = s * (1.f / 256.f);
      float var = ss * (1.f / 256.f) - mean * mean;
      float inv = rsqrtf(var + 1e-5f);
#pragma unroll
      for (int ni = 0; ni < 4; ++ni) {
        float v = (acc2[mi][ni][j] - mean) * inv * gcol[ni] + zcol[ni];
        acc2[mi][ni][j] = v > 0.f ? v : 0.f;
      }
    }
  }
#pragma unroll
  for (int ni = 0; ni < 4; ++ni) {
    float cs = 0.f;
#pragma unroll
    for (int mi = 0; mi < 4; ++mi) {
#pragma unroll
      for (int j = 0; j < 4; ++j) cs += acc2[mi][ni][j];
    }
    cs += __shfl_xor(cs, 16);
    cs += __shfl_xor(cs, 32);
    if (q == 0) {
      int col = wc * 64 + ni * 16 + lr;
      gpart[(((size_t)b * NMB + mb) * 2 + wr) * 256 + col] = cs;
    }
  }
}

__global__ void k_readout(const float* __restrict__ gpart, const float* __restrict__ Wa,
                          const float* __restrict__ ba, const float* __restrict__ Wl,
                          const float* __restrict__ bl, float* __restrict__ out) {
  __shared__ float gl[256];
  int b = blockIdx.x, t = threadIdx.x;  // 256 threads
  float s = 0.f;
#pragma unroll 4
  for (int p = 0; p < 32; ++p) s += gpart[((size_t)b * 32 + p) * 256 + t];
  gl[t] = s * (1.f / 2048.f);
  __syncthreads();
  if (t < 128) {
    int k = t & 63;
    const float* W = (t >= 64) ? Wl : Wa;
    const float* bb = (t >= 64) ? bl : ba;
    float a = 0.f;
    for (int h = 0; h < 256; ++h) a += gl[h] * W[h * 64 + k];
    a += bb[k];
    out[((t >= 64) ? 2048 : 0) + b * 64 + k] = a;
  }
}

extern "C" void kernel_launch(void* const* d_in, const int* in_sizes, int n_in,
                              void* d_out, int out_size, void* d_ws, size_t ws_size,
                              hipStream_t stream) {
  const float* A_hat = (const float*)d_in[0];
  const float* X   = (const float*)d_in[1];
  const float* W1  = (const float*)d_in[2];
  const float* b1  = (const float*)d_in[3];
  const float* g1  = (const float*)d_in[4];
  const float* be1 = (const float*)d_in[5];
  const float* W2  = (const float*)d_in[6];
  const float* b2  = (const float*)d_in[7];
  const float* g2  = (const float*)d_in[8];
  const float* be2 = (const float*)d_in[9];
  const float* Wa  = (const float*)d_in[10];
  const float* ba  = (const float*)d_in[11];
  const float* Wl  = (const float*)d_in[12];
  const float* bl  = (const float*)d_in[13];

  char* ws = (char*)d_ws;
  const size_t MB = 1024 * 1024;
  unsigned short* XT  = (unsigned short*)(ws);                         // 16 MiB (B,128,2048)
  unsigned short* H1T = (unsigned short*)(ws + 16 * MB);               // 32 MiB (B,256,2048)
  unsigned short* W1T = (unsigned short*)(ws + 48 * MB);               // 64 KB (256x128)
  unsigned short* W2T = (unsigned short*)(ws + 48 * MB + 256 * 1024);  // 128 KB (256x256)
  float* gpart        = (float*)(ws + 49 * MB);                        // 1 MiB (B,32,256)

  // prep: transposed bf16 copies (X + W1 + W2 in one launch)
  k_tr_all<<<dim3(8288), 256, 0, stream>>>(X, XT, W1, W1T, W2, W2T);
  // layer 1 fused (R7-proven): H1T = relu(LN(A@X @ W1 + b1))^T
  k_agg_fused<128, 0><<<dim3(16, 1, 32), 512, 0, stream>>>(
      A_hat, XT, W1T, b1, g1, be1, H1T, nullptr);
  // layer 2 fused, 80 KB LDS -> 2 blocks/CU
  k_agg2<<<dim3(16, 1, 32), 512, 0, stream>>>(
      A_hat, H1T, W2T, b2, g2, be2, gpart);
  // readout
  k_readout<<<dim3(32), 256, 0, stream>>>(gpart, Wa, ba, Wl, bl, (float*)d_out);
}

// Round 11
// 325.090 us; speedup vs baseline: 1.6578x; 1.0178x over previous
//
#include <hip/hip_runtime.h>
#include <hip/hip_bf16.h>

#define NN 2048

typedef __attribute__((ext_vector_type(4))) float f32x4;
typedef __attribute__((ext_vector_type(8))) short bf16x8;

__device__ __forceinline__ unsigned short f2bf(float f) {
  __hip_bfloat16 h = __float2bfloat16(f);
  return __builtin_bit_cast(unsigned short, h);
}
__device__ __forceinline__ unsigned int pk2(float a, float b) {
  return (unsigned int)f2bf(a) | ((unsigned int)f2bf(b) << 16);
}
__device__ __forceinline__ void gld_lds16(const void* g, void* l) {
  __builtin_amdgcn_global_load_lds(
      (const __attribute__((address_space(1))) unsigned int*)g,
      (__attribute__((address_space(3))) unsigned int*)l, 16, 0, 0);
}

// Merged transpose+cvt: f32 (R x C) -> bf16 (C x R) for X (batched), W1, W2.
__global__ void k_tr_all(const float* __restrict__ X, unsigned short* __restrict__ XT,
                         const float* __restrict__ W1, unsigned short* __restrict__ W1T,
                         const float* __restrict__ W2, unsigned short* __restrict__ W2T) {
  int bid = blockIdx.x;
  const float* src;
  unsigned short* dst;
  int R, C, bx, by, b;
  if (bid < 8192) {  // X: per batch 64 x 4 tiles, 32 batches
    src = X; dst = XT; R = 2048; C = 128;
    b = bid >> 8;
    int r = bid & 255;
    bx = r & 63; by = r >> 6;
  } else if (bid < 8192 + 32) {  // W1: 128 x 256 -> 4 x 8 tiles
    src = W1; dst = W1T; R = 128; C = 256; b = 0;
    int r = bid - 8192;
    bx = r & 3; by = r >> 2;
  } else {  // W2: 256 x 256 -> 8 x 8 tiles
    src = W2; dst = W2T; R = 256; C = 256; b = 0;
    int r = bid - 8224;
    bx = r & 7; by = r >> 3;
  }
  src += (size_t)b * R * C;
  dst += (size_t)b * R * C;
  __shared__ float tile[32][33];
  int r0 = bx * 32, c0 = by * 32;
  int t = threadIdx.x;
  int r = t >> 3, c4 = (t & 7) << 2;
  float4 v = *(const float4*)(src + (size_t)(r0 + r) * C + c0 + c4);
  tile[r][c4 + 0] = v.x; tile[r][c4 + 1] = v.y; tile[r][c4 + 2] = v.z; tile[r][c4 + 3] = v.w;
  __syncthreads();
  ushort4 o;
  o.x = f2bf(tile[c4 + 0][r]); o.y = f2bf(tile[c4 + 1][r]);
  o.z = f2bf(tile[c4 + 2][r]); o.w = f2bf(tile[c4 + 3][r]);
  *(ushort4*)(dst + (size_t)(c0 + r) * R + r0 + c4) = o;
}

// ---------------- Layer-1 fused kernel (R7-proven, unchanged) ----------------
#define AGG_STEP(KT, AREGC, AREGN, CUR, VMC)                                   \
  {                                                                            \
    const int kt_ = (KT);                                                      \
    if (kt_ < NKT - 1) { /* B tile kt+1 -> Bs[nxt]; issued first (oldest) */   \
      _Pragma("unroll") for (int i = 0; i < NF; ++i) {                         \
        int jj = i * 512 + t;                                                  \
        int n_ = jj >> 3, s_ = jj & 7, sp_ = s_ ^ (n_ & 7);                    \
        gld_lds16(BTb + (size_t)n_ * NN + (size_t)(kt_ + 1) * 64 + sp_ * 8,    \
                  &Bs[(CUR) ^ 1][(i * 512 + wid * 64) * 8]);                   \
      }                                                                        \
    }                                                                          \
    __builtin_amdgcn_sched_barrier(0); /* pin: B ops issue before A ops */     \
    if (kt_ < NKT - 2) { /* A loads for kt+2; stay in flight over barrier */   \
      const float* p_ = apb + (size_t)(kt_ + 2) * 64;                          \
      _Pragma("unroll") for (int j = 0; j < 4; ++j)                            \
          AREGN[j] = ((const float4*)p_)[j];                                   \
    }                                                                          \
    if (kt_ < NKT - 1) { /* cvt A(kt+1) regs (landed long ago) -> As[nxt] */   \
      _Pragma("unroll") for (int i = 0; i < 2; ++i) {                          \
        uint4 w_;                                                              \
        w_.x = pk2(AREGC[2 * i].x, AREGC[2 * i].y);                            \
        w_.y = pk2(AREGC[2 * i].z, AREGC[2 * i].w);                            \
        w_.z = pk2(AREGC[2 * i + 1].x, AREGC[2 * i + 1].y);                    \
        w_.w = pk2(AREGC[2 * i + 1].z, AREGC[2 * i + 1].w);                    \
        int s_ = ak * 2 + i, sp_ = s_ ^ (ar & 7);                              \
        *(uint4*)&As[(CUR) ^ 1][(ar * 8 + sp_) * 8] = w_;                      \
      }                                                                        \
    }                                                                          \
    _Pragma("unroll") for (int kh = 0; kh < 2; ++kh) {                         \
      bf16x8 af[4], bfr[NF];                                                   \
      _Pragma("unroll") for (int mi = 0; mi < 4; ++mi) {                       \
        int row = wr * 64 + mi * 16 + lr;                                      \
        int sp_ = (kh * 4 + q) ^ (row & 7);                                    \
        af[mi] = *(const bf16x8*)&As[CUR][(row * 8 + sp_) * 8];                \
      }                                                                        \
      _Pragma("unroll") for (int ni = 0; ni < NF; ++ni) {                      \
        int brow = wc * WN + ni * 16 + lr;                                     \
        int sp_ = (kh * 4 + q) ^ (brow & 7);                                   \
        bfr[ni] = *(const bf16x8*)&Bs[CUR][(brow * 8 + sp_) * 8];              \
      }                                                                        \
      _Pragma("unroll") for (int mi = 0; mi < 4; ++mi)                         \
        _Pragma("unroll") for (int ni = 0; ni < NF; ++ni)                      \
          acc[mi][ni] = __builtin_amdgcn_mfma_f32_16x16x32_bf16(               \
              af[mi], bfr[ni], acc[mi][ni], 0, 0, 0);                          \
    }                                                                          \
    asm volatile("s_waitcnt vmcnt(" #VMC ") lgkmcnt(0)" ::: "memory");         \
    __builtin_amdgcn_s_barrier();                                              \
  }

template <int NCOLS, int MODE>
__global__ __launch_bounds__(512, NCOLS == 128 ? 4 : 2) void k_agg_fused(
    const float* __restrict__ A, const unsigned short* __restrict__ BT,
    const unsigned short* __restrict__ WT, const float* __restrict__ bias,
    const float* __restrict__ gamma, const float* __restrict__ beta,
    unsigned short* __restrict__ HTout, float* __restrict__ gpart) {
  constexpr int WN = NCOLS / 4;
  constexpr int NF = NCOLS / 64;
  constexpr int NKT = NN / 64;
  constexpr int FIN = NCOLS;
  constexpr int NQT = FIN / 64;
  constexpr int NMB = NN / 128;

  __shared__ __align__(16) unsigned short As[2][128 * 64];
  __shared__ __align__(16) unsigned short Bs[2][NCOLS * 64];
  __shared__ float red[2][128][4];

  int L = blockIdx.x + gridDim.x * blockIdx.z;
  int xcd = L & 7, slot = L >> 3;
  int mb = slot % NMB;
  int b = xcd + 8 * (slot / NMB);
  int m0 = mb * 128;

  const float* Ab = A + (size_t)b * NN * NN;
  const unsigned short* BTb = BT + (size_t)b * (size_t)NCOLS * NN;
  int t = threadIdx.x, lane = t & 63, wid = t >> 6;
  int wr = wid >> 2, wc = wid & 3;
  int q = lane >> 4, lr = lane & 15;
  int ar = t >> 2, ak = t & 3;
  const float* apb = Ab + (size_t)(m0 + ar) * NN + ak * 16;

  f32x4 acc[4][NF] = {};
  float4 aregA[4], aregB[4];

  {
#pragma unroll
    for (int j = 0; j < 4; ++j) aregA[j] = ((const float4*)apb)[j];
#pragma unroll
    for (int i = 0; i < NF; ++i) {
      int jj = i * 512 + t;
      int n = jj >> 3, s = jj & 7, sp = s ^ (n & 7);
      gld_lds16(BTb + (size_t)n * NN + sp * 8, &Bs[0][(i * 512 + wid * 64) * 8]);
    }
#pragma unroll
    for (int i = 0; i < 2; ++i) {
      uint4 w;
      w.x = pk2(aregA[2 * i].x, aregA[2 * i].y);
      w.y = pk2(aregA[2 * i].z, aregA[2 * i].w);
      w.z = pk2(aregA[2 * i + 1].x, aregA[2 * i + 1].y);
      w.w = pk2(aregA[2 * i + 1].z, aregA[2 * i + 1].w);
      int s = ak * 2 + i, sp = s ^ (ar & 7);
      *(uint4*)&As[0][(ar * 8 + sp) * 8] = w;
    }
    __builtin_amdgcn_sched_barrier(0);
#pragma unroll
    for (int j = 0; j < 4; ++j) aregB[j] = ((const float4*)(apb + 64))[j];
    asm volatile("s_waitcnt vmcnt(4) lgkmcnt(0)" ::: "memory");
    __builtin_amdgcn_s_barrier();
  }

  for (int k2 = 0; k2 < NKT / 2 - 1; ++k2) {
    AGG_STEP(2 * k2, aregB, aregA, 0, 4);
    AGG_STEP(2 * k2 + 1, aregA, aregB, 1, 4);
  }
  AGG_STEP(NKT - 2, aregB, aregA, 0, 0);
  AGG_STEP(NKT - 1, aregA, aregB, 1, 0);

  unsigned short* Hs = (NCOLS == 128) ? &As[0][0] : &Bs[0][0];
  unsigned short* Ws = (NCOLS == 128) ? &Bs[0][0] : &As[0][0];
#pragma unroll
  for (int mi = 0; mi < 4; ++mi) {
#pragma unroll
    for (int ni = 0; ni < NF; ++ni) {
#pragma unroll
      for (int j = 0; j < 4; ++j) {
        int row = wr * 64 + mi * 16 + q * 4 + j;
        int col = wc * WN + ni * 16 + lr;
        int sp = (col >> 3) ^ (row & 7);
        Hs[row * FIN + sp * 8 + (col & 7)] = f2bf(acc[mi][ni][j]);
      }
    }
  }

  f32x4 acc2[4][4] = {};
  for (int qt = 0; qt < NQT; ++qt) {
    __syncthreads();
#pragma unroll
    for (int i = 0; i < 4; ++i) {
      int jj = i * 512 + t;
      int h = jj >> 3, s = jj & 7, sp = s ^ (h & 7);
      gld_lds16(WT + (size_t)h * FIN + qt * 64 + sp * 8, Ws + (i * 512 + wid * 64) * 8);
    }
    __syncthreads();
#pragma unroll
    for (int kh = 0; kh < 2; ++kh) {
      bf16x8 hf[4], wf[4];
#pragma unroll
      for (int mi = 0; mi < 4; ++mi) {
        int row = wr * 64 + mi * 16 + lr;
        int slotk = qt * 8 + kh * 4 + q;
        int sp = slotk ^ (row & 7);
        hf[mi] = *(const bf16x8*)&Hs[row * FIN + sp * 8];
      }
#pragma unroll
      for (int ni = 0; ni < 4; ++ni) {
        int h = wc * 64 + ni * 16 + lr;
        int sp = (kh * 4 + q) ^ (h & 7);
        wf[ni] = *(const bf16x8*)&Ws[(h * 8 + sp) * 8];
      }
#pragma unroll
      for (int mi = 0; mi < 4; ++mi) {
#pragma unroll
        for (int ni = 0; ni < 4; ++ni)
          acc2[mi][ni] = __builtin_amdgcn_mfma_f32_16x16x32_bf16(hf[mi], wf[ni], acc2[mi][ni], 0, 0, 0);
      }
    }
  }

  float bcol[4], gcol[4], zcol[4];
#pragma unroll
  for (int ni = 0; ni < 4; ++ni) {
    int col = wc * 64 + ni * 16 + lr;
    bcol[ni] = bias[col]; gcol[ni] = gamma[col]; zcol[ni] = beta[col];
  }
#pragma unroll
  for (int mi = 0; mi < 4; ++mi) {
#pragma unroll
    for (int j = 0; j < 4; ++j) {
      float s = 0.f, ss = 0.f;
#pragma unroll
      for (int ni = 0; ni < 4; ++ni) {
        float v = acc2[mi][ni][j] + bcol[ni];
        acc2[mi][ni][j] = v;
        s += v; ss += v * v;
      }
#pragma unroll
      for (int m = 1; m < 16; m <<= 1) { s += __shfl_xor(s, m); ss += __shfl_xor(ss, m); }
      if (lr == 0) {
        int rl = wr * 64 + mi * 16 + q * 4 + j;
        red[0][rl][wc] = s;
        red[1][rl][wc] = ss;
      }
    }
  }
  __syncthreads();
#pragma unroll
  for (int mi = 0; mi < 4; ++mi) {
#pragma unroll
    for (int j = 0; j < 4; ++j) {
      int rl = wr * 64 + mi * 16 + q * 4 + j;
      float s = red[0][rl][0] + red[0][rl][1] + red[0][rl][2] + red[0][rl][3];
      float ss = red[1][rl][0] + red[1][rl][1] + red[1][rl][2] + red[1][rl][3];
      float mean = s * (1.f / 256.f);
      float var = ss * (1.f / 256.f) - mean * mean;
      float inv = rsqrtf(var + 1e-5f);
#pragma unroll
      for (int ni = 0; ni < 4; ++ni) {
        float v = (acc2[mi][ni][j] - mean) * inv * gcol[ni] + zcol[ni];
        acc2[mi][ni][j] = v > 0.f ? v : 0.f;
      }
    }
  }
  if (MODE == 0) {
#pragma unroll
    for (int mi = 0; mi < 4; ++mi) {
#pragma unroll
      for (int ni = 0; ni < 4; ++ni) {
        int col = wc * 64 + ni * 16 + lr;
        int rowb = m0 + wr * 64 + mi * 16 + q * 4;
        ushort4 o;
        o.x = f2bf(acc2[mi][ni][0]); o.y = f2bf(acc2[mi][ni][1]);
        o.z = f2bf(acc2[mi][ni][2]); o.w = f2bf(acc2[mi][ni][3]);
        *(ushort4*)(HTout + ((size_t)b * 256 + col) * NN + rowb) = o;
      }
    }
  } else {
#pragma unroll
    for (int ni = 0; ni < 4; ++ni) {
      float cs = 0.f;
#pragma unroll
      for (int mi = 0; mi < 4; ++mi) {
#pragma unroll
        for (int j = 0; j < 4; ++j) cs += acc2[mi][ni][j];
      }
      cs += __shfl_xor(cs, 16);
      cs += __shfl_xor(cs, 32);
      if (q == 0) {
        int col = wc * 64 + ni * 16 + lr;
        gpart[(((size_t)b * NMB + mb) * 2 + wr) * 256 + col] = cs;
      }
    }
  }
}

// ---- Layer-2: R7 structure + TRIPLE-buffered B (2-step B prefetch) ----
// Per step kt: stage B(kt+2)->bS, issue A(kt+2)->regs, cvt A(kt+1)->As[nxt],
// MFMA(As[cur], bR), s_waitcnt vmcnt(8) (leaves B(kt+2)+A(kt+2) in flight),
// one barrier. Every B-tile gets ~2 steps of latency cover at 1 blk/CU.
#define AGG2_STEP(KT, AREGC, AREGN, BR, BS_, VMC)                              \
  {                                                                            \
    const int kt_ = (KT);                                                      \
    if (kt_ < 30) { /* B tile kt+2 -> BS_ (oldest vmem ops of this step) */    \
      _Pragma("unroll") for (int i = 0; i < 4; ++i) {                          \
        int jj = i * 512 + t;                                                  \
        int n_ = jj >> 3, s_ = jj & 7, sp_ = s_ ^ (n_ & 7);                    \
        gld_lds16(BTb + (size_t)n_ * NN + (size_t)(kt_ + 2) * 64 + sp_ * 8,    \
                  (BS_) + (i * 512 + wid * 64) * 8);                           \
      }                                                                        \
    }                                                                          \
    __builtin_amdgcn_sched_barrier(0); /* pin: B ops issue before A ops */     \
    if (kt_ < 30) { /* A loads for kt+2 */                                     \
      const float* p_ = apb + (size_t)(kt_ + 2) * 64;                          \
      _Pragma("unroll") for (int j = 0; j < 4; ++j)                            \
          AREGN[j] = ((const float4*)p_)[j];                                   \
    }                                                                          \
    if (kt_ < 31) { /* cvt A(kt+1) -> As[(kt+1)&1] */                          \
      _Pragma("unroll") for (int i = 0; i < 2; ++i) {                          \
        uint4 w_;                                                              \
        w_.x = pk2(AREGC[2 * i].x, AREGC[2 * i].y);                            \
        w_.y = pk2(AREGC[2 * i].z, AREGC[2 * i].w);                            \
        w_.z = pk2(AREGC[2 * i + 1].x, AREGC[2 * i + 1].y);                    \
        w_.w = pk2(AREGC[2 * i + 1].z, AREGC[2 * i + 1].w);                    \
        int s_ = ak * 2 + i, sp_ = s_ ^ (ar & 7);                              \
        *(uint4*)&As[(kt_ + 1) & 1][(ar * 8 + sp_) * 8] = w_;                  \
      }                                                                        \
    }                                                                          \
    _Pragma("unroll") for (int kh = 0; kh < 2; ++kh) {                         \
      bf16x8 af[4], bfr[4];                                                    \
      _Pragma("unroll") for (int mi = 0; mi < 4; ++mi) {                       \
        int row = wr * 64 + mi * 16 + lr;                                      \
        int sp_ = (kh * 4 + q) ^ (row & 7);                                    \
        af[mi] = *(const bf16x8*)&As[(KT) & 1][(row * 8 + sp_) * 8];           \
      }                                                                        \
      _Pragma("unroll") for (int ni = 0; ni < 4; ++ni) {                       \
        int brow = wc * 64 + ni * 16 + lr;                                     \
        int sp_ = (kh * 4 + q) ^ (brow & 7);                                   \
        bfr[ni] = *(const bf16x8*)((BR) + (brow * 8 + sp_) * 8);               \
      }                                                                        \
      _Pragma("unroll") for (int mi = 0; mi < 4; ++mi)                         \
        _Pragma("unroll") for (int ni = 0; ni < 4; ++ni)                       \
          acc[mi][ni] = __builtin_amdgcn_mfma_f32_16x16x32_bf16(               \
              af[mi], bfr[ni], acc[mi][ni], 0, 0, 0);                          \
    }                                                                          \
    asm volatile("s_waitcnt vmcnt(" #VMC ") lgkmcnt(0)" ::: "memory");         \
    __builtin_amdgcn_s_barrier();                                              \
  }

#define ROT3() { unsigned short* tmp_ = bR; bR = bM; bM = bS; bS = tmp_; }

__global__ __launch_bounds__(512, 2) void k_agg2(
    const float* __restrict__ A, const unsigned short* __restrict__ BT,
    const unsigned short* __restrict__ WT, const float* __restrict__ bias,
    const float* __restrict__ gamma, const float* __restrict__ beta,
    float* __restrict__ gpart) {
  constexpr int NMB = 16;

  __shared__ __align__(16) unsigned short As[2][128 * 64];  // 32 KB
  __shared__ __align__(16) unsigned short Bsb[3][256 * 64]; // 96 KB
  __shared__ float red[2][128][4];                          // 4 KB

  int L = blockIdx.x + gridDim.x * blockIdx.z;
  int xcd = L & 7, slot = L >> 3;
  int mb = slot % NMB;
  int b = xcd + 8 * (slot / NMB);
  int m0 = mb * 128;

  const float* Ab = A + (size_t)b * NN * NN;
  const unsigned short* BTb = BT + (size_t)b * (size_t)256 * NN;
  int t = threadIdx.x, lane = t & 63, wid = t >> 6;
  int wr = wid >> 2, wc = wid & 3;
  int q = lane >> 4, lr = lane & 15;
  int ar = t >> 2, ak = t & 3;
  const float* apb = Ab + (size_t)(m0 + ar) * NN + ak * 16;

  f32x4 acc[4][4] = {};
  float4 aregA[4], aregB[4];
  unsigned short* bR = &Bsb[0][0];
  unsigned short* bM = &Bsb[1][0];
  unsigned short* bS = &Bsb[2][0];

  // prologue: A(0)->aregA, B(0)->Bsb0, cvt A(0)->As[0], A(1)->aregB,
  // B(1)->Bsb1; vmcnt(8) leaves A(1)+B(1) in flight; barrier.
  {
#pragma unroll
    for (int j = 0; j < 4; ++j) aregA[j] = ((const float4*)apb)[j];
#pragma unroll
    for (int i = 0; i < 4; ++i) {
      int jj = i * 512 + t;
      int n = jj >> 3, s = jj & 7, sp = s ^ (n & 7);
      gld_lds16(BTb + (size_t)n * NN + sp * 8, bR + (i * 512 + wid * 64) * 8);
    }
#pragma unroll
    for (int i = 0; i < 2; ++i) {
      uint4 w;
      w.x = pk2(aregA[2 * i].x, aregA[2 * i].y);
      w.y = pk2(aregA[2 * i].z, aregA[2 * i].w);
      w.z = pk2(aregA[2 * i + 1].x, aregA[2 * i + 1].y);
      w.w = pk2(aregA[2 * i + 1].z, aregA[2 * i + 1].w);
      int s = ak * 2 + i, sp = s ^ (ar & 7);
      *(uint4*)&As[0][(ar * 8 + sp) * 8] = w;
    }
    __builtin_amdgcn_sched_barrier(0);
#pragma unroll
    for (int j = 0; j < 4; ++j) aregB[j] = ((const float4*)(apb + 64))[j];
#pragma unroll
    for (int i = 0; i < 4; ++i) {
      int jj = i * 512 + t;
      int n = jj >> 3, s = jj & 7, sp = s ^ (n & 7);
      gld_lds16(BTb + (size_t)n * NN + 64 + sp * 8, bM + (i * 512 + wid * 64) * 8);
    }
    asm volatile("s_waitcnt vmcnt(8) lgkmcnt(0)" ::: "memory");
    __builtin_amdgcn_s_barrier();
  }

  for (int k2 = 0; k2 < 15; ++k2) {
    AGG2_STEP(2 * k2, aregB, aregA, bR, bS, 8);
    ROT3();
    AGG2_STEP(2 * k2 + 1, aregA, aregB, bR, bS, 8);
    ROT3();
  }
  AGG2_STEP(30, aregB, aregA, bR, bS, 0);
  ROT3();
  AGG2_STEP(31, aregA, aregB, bR, bS, 0);

  // ---- epilogue (R7-identical): T(128 x 256) -> Hs; W^T in quarters ----
  unsigned short* Hs = &Bsb[0][0];
  unsigned short* Ws = &As[0][0];
#pragma unroll
  for (int mi = 0; mi < 4; ++mi) {
#pragma unroll
    for (int ni = 0; ni < 4; ++ni) {
#pragma unroll
      for (int j = 0; j < 4; ++j) {
        int row = wr * 64 + mi * 16 + q * 4 + j;
        int col = wc * 64 + ni * 16 + lr;
        int sp = (col >> 3) ^ (row & 7);
        Hs[row * 256 + sp * 8 + (col & 7)] = f2bf(acc[mi][ni][j]);
      }
    }
  }

  f32x4 acc2[4][4] = {};
  for (int qt = 0; qt < 4; ++qt) {
    __syncthreads();
#pragma unroll
    for (int i = 0; i < 4; ++i) {
      int jj = i * 512 + t;
      int h = jj >> 3, s = jj & 7, sp = s ^ (h & 7);
      gld_lds16(WT + (size_t)h * 256 + qt * 64 + sp * 8, Ws + (i * 512 + wid * 64) * 8);
    }
    __syncthreads();
#pragma unroll
    for (int kh = 0; kh < 2; ++kh) {
      bf16x8 hf[4], wf[4];
#pragma unroll
      for (int mi = 0; mi < 4; ++mi) {
        int row = wr * 64 + mi * 16 + lr;
        int slotk = qt * 8 + kh * 4 + q;
        int sp = slotk ^ (row & 7);
        hf[mi] = *(const bf16x8*)&Hs[row * 256 + sp * 8];
      }
#pragma unroll
      for (int ni = 0; ni < 4; ++ni) {
        int h = wc * 64 + ni * 16 + lr;
        int sp = (kh * 4 + q) ^ (h & 7);
        wf[ni] = *(const bf16x8*)&Ws[(h * 8 + sp) * 8];
      }
#pragma unroll
      for (int mi = 0; mi < 4; ++mi) {
#pragma unroll
        for (int ni = 0; ni < 4; ++ni)
          acc2[mi][ni] = __builtin_amdgcn_mfma_f32_16x16x32_bf16(hf[mi], wf[ni], acc2[mi][ni], 0, 0, 0);
      }
    }
  }

  float bcol[4], gcol[4], zcol[4];
#pragma unroll
  for (int ni = 0; ni < 4; ++ni) {
    int col = wc * 64 + ni * 16 + lr;
    bcol[ni] = bias[col]; gcol[ni] = gamma[col]; zcol[ni] = beta[col];
  }
#pragma unroll
  for (int mi = 0; mi < 4; ++mi) {
#pragma unroll
    for (int j = 0; j < 4; ++j) {
      float s = 0.f, ss = 0.f;
#pragma unroll
      for (int ni = 0; ni < 4; ++ni) {
        float v = acc2[mi][ni][j] + bcol[ni];
        acc2[mi][ni][j] = v;
        s += v; ss += v * v;
      }
#pragma unroll
      for (int m = 1; m < 16; m <<= 1) { s += __shfl_xor(s, m); ss += __shfl_xor(ss, m); }
      if (lr == 0) {
        int rl = wr * 64 + mi * 16 + q * 4 + j;
        red[0][rl][wc] = s;
        red[1][rl][wc] = ss;
      }
    }
  }
  __syncthreads();
#pragma unroll
  for (int mi = 0; mi < 4; ++mi) {
#pragma unroll
    for (int j = 0; j < 4; ++j) {
      int rl = wr * 64 + mi * 16 + q * 4 + j;
      float s = red[0][rl][0] + red[0][rl][1] + red[0][rl][2] + red[0][rl][3];
      float ss = red[1][rl][0] + red[1][rl][1] + red[1][rl][2] + red[1][rl][3];
      float mean = s * (1.f / 256.f);
      float var = ss * (1.f / 256.f) - mean * mean;
      float inv = rsqrtf(var + 1e-5f);
#pragma unroll
      for (int ni = 0; ni < 4; ++ni) {
        float v = (acc2[mi][ni][j] - mean) * inv * gcol[ni] + zcol[ni];
        acc2[mi][ni][j] = v > 0.f ? v : 0.f;
      }
    }
  }
#pragma unroll
  for (int ni = 0; ni < 4; ++ni) {
    float cs = 0.f;
#pragma unroll
    for (int mi = 0; mi < 4; ++mi) {
#pragma unroll
      for (int j = 0; j < 4; ++j) cs += acc2[mi][ni][j];
    }
    cs += __shfl_xor(cs, 16);
    cs += __shfl_xor(cs, 32);
    if (q == 0) {
      int col = wc * 64 + ni * 16 + lr;
      gpart[(((size_t)b * NMB + mb) * 2 + wr) * 256 + col] = cs;
    }
  }
}

__global__ void k_readout(const float* __restrict__ gpart, const float* __restrict__ Wa,
                          const float* __restrict__ ba, const float* __restrict__ Wl,
                          const float* __restrict__ bl, float* __restrict__ out) {
  __shared__ float gl[256];
  int b = blockIdx.x, t = threadIdx.x;  // 256 threads
  float s = 0.f;
#pragma unroll 4
  for (int p = 0; p < 32; ++p) s += gpart[((size_t)b * 32 + p) * 256 + t];
  gl[t] = s * (1.f / 2048.f);
  __syncthreads();
  if (t < 128) {
    int k = t & 63;
    const float* W = (t >= 64) ? Wl : Wa;
    const float* bb = (t >= 64) ? bl : ba;
    float a = 0.f;
    for (int h = 0; h < 256; ++h) a += gl[h] * W[h * 64 + k];
    a += bb[k];
    out[((t >= 64) ? 2048 : 0) + b * 64 + k] = a;
  }
}

extern "C" void kernel_launch(void* const* d_in, const int* in_sizes, int n_in,
                              void* d_out, int out_size, void* d_ws, size_t ws_size,
                              hipStream_t stream) {
  const float* A_hat = (const float*)d_in[0];
  const float* X   = (const float*)d_in[1];
  const float* W1  = (const float*)d_in[2];
  const float* b1  = (const float*)d_in[3];
  const float* g1  = (const float*)d_in[4];
  const float* be1 = (const float*)d_in[5];
  const float* W2  = (const float*)d_in[6];
  const float* b2  = (const float*)d_in[7];
  const float* g2  = (const float*)d_in[8];
  const float* be2 = (const float*)d_in[9];
  const float* Wa  = (const float*)d_in[10];
  const float* ba  = (const float*)d_in[11];
  const float* Wl  = (const float*)d_in[12];
  const float* bl  = (const float*)d_in[13];

  char* ws = (char*)d_ws;
  const size_t MB = 1024 * 1024;
  unsigned short* XT  = (unsigned short*)(ws);                         // 16 MiB (B,128,2048)
  unsigned short* H1T = (unsigned short*)(ws + 16 * MB);               // 32 MiB (B,256,2048)
  unsigned short* W1T = (unsigned short*)(ws + 48 * MB);               // 64 KB (256x128)
  unsigned short* W2T = (unsigned short*)(ws + 48 * MB + 256 * 1024);  // 128 KB (256x256)
  float* gpart        = (float*)(ws + 49 * MB);                        // 1 MiB (B,32,256)

  // prep: transposed bf16 copies (X + W1 + W2 in one launch)
  k_tr_all<<<dim3(8288), 256, 0, stream>>>(X, XT, W1, W1T, W2, W2T);
  // layer 1 fused (R7-proven): H1T = relu(LN(A@X @ W1 + b1))^T
  k_agg_fused<128, 0><<<dim3(16, 1, 32), 512, 0, stream>>>(
      A_hat, XT, W1T, b1, g1, be1, H1T, nullptr);
  // layer 2 fused, triple-buffered B (2-step prefetch depth)
  k_agg2<<<dim3(16, 1, 32), 512, 0, stream>>>(
      A_hat, H1T, W2T, b2, g2, be2, gpart);
  // readout
  k_readout<<<dim3(32), 256, 0, stream>>>(gpart, Wa, ba, Wl, bl, (float*)d_out);
}